// Round 9
// baseline (1149.928 us; speedup 1.0000x reference)
//
#include <hip/hip_runtime.h>
#include <hip/hip_cooperative_groups.h>
#include <stdint.h>

namespace cg = cooperative_groups;

namespace {

constexpr int B = 8;
constexpr int H = 1024;
constexpr int W = 1024;
constexpr int TOPK = 4096;
constexpr int CAND_CAP = 131072;  // per batch
constexpr int SEL_CAP = 16384;    // per batch
constexpr int LIST_CAP = 320;     // per 64x64 tile
constexpr int NSL = 128;          // hist/compact slices per batch (8*128 = 1024 units)

// fused-NMS tile: 64x64 interior, radius-12 staged halo (validity chain: see r1-r8).
constexpr int RROWS = 92;
constexpr int NG = 22;
constexpr int STR = 88;
constexpr int MW = 5;       // mask row stride (bank-conflict pad, round-8: 5.06M->3.97M)
constexpr int NSTRIP = 11;
constexpr int NUNIT = NG * NSTRIP;  // 242

// workspace layout (bytes)
constexpr size_t OFF_CNT   = 0;                                   // 4 KiB
constexpr size_t OFF_EH    = 4096;                                // B*256*4
constexpr size_t OFF_FH    = OFF_EH + (size_t)B * 256 * 4;
constexpr size_t OFF_RANK  = OFF_FH + (size_t)B * 256 * 4;        // zeroed by compact
constexpr size_t OFF_SEL   = OFF_RANK + (size_t)B * SEL_CAP * 4;
constexpr size_t OFF_CAND  = OFF_SEL + (size_t)B * SEL_CAP * 8;

// shared memory overlay (max over phases = NMS: 32384 + 2*1840 + 2560 = 38624)
constexpr int SMEM_BYTES = 38656;

__device__ __forceinline__ float max5(float a, float b, float c, float d, float e) {
  return fmaxf(fmaxf(fmaxf(a, b), fmaxf(c, d)), e);
}
__device__ __forceinline__ float4 ld4(const float* p) {
  return *reinterpret_cast<const float4*>(p);
}

template <int PASS>
__device__ __forceinline__ void score_pass(
    int u, int x0, int y0, const float* __restrict__ S,
    const uint32_t* __restrict__ MIN_, uint32_t* __restrict__ MOUT,
    uint64_t* list, uint32_t* cnt_loc, uint64_t* cand, uint32_t* cand_count, int b) {
  const int G = u % NG, s = u / NG;
  const int r0 = 2 + 8 * s;
  const int gx0 = x0 - 12 + 4 * G;
  uint32_t colm = 0;
#pragma unroll
  for (int j = 0; j < 4; ++j)
    if ((unsigned)(gx0 + j) < (unsigned)W) colm |= 1u << j;

  const int p2 = 4 * G - 6;
  const int pw2 = (p2 < 0) ? 0 : (p2 >> 5);
  const int psh2 = (p2 < 0) ? 0 : (p2 & 31);
  const int pls2 = (p2 < 0) ? -p2 : 0;

  float4 hw[5], cw[5];
  uint32_t snr[5], mor[5], cnb[5];
  constexpr int NK = (PASS == 0) ? 12 : 16;
#pragma unroll
  for (int k = 0; k < NK; ++k) {
    if (PASS != 0) {
      const int mr = r0 - 4 + k;
      uint32_t morrow = 0, cnib = 0;
      if ((unsigned)mr < (unsigned)RROWS) {
        const uint32_t* srow = MIN_ + mr * MW;
        uint64_t X = (uint64_t)srow[pw2] | ((uint64_t)srow[pw2 + 1] << 32);
        uint64_t win = pls2 ? (X << pls2) : (X >> psh2);
        uint64_t t5 = win | (win >> 1) | (win >> 2) | (win >> 3) | (win >> 4);
        morrow = (uint32_t)t5 & 0xFFFu;
        cnib = (uint32_t)(win >> 6) & 0xFu;
      }
      mor[k % 5] = morrow;
      cnb[k % 5] = cnib;
    }
    const int ks = (PASS == 0) ? k : k - 4;
    if (ks >= 0) {
      const int sr = r0 - 2 + ks;
      uint32_t supp = 0;
      if (PASS != 0) supp = mor[0] | mor[1] | mor[2] | mor[3] | mor[4];
      const float* rowp = S + sr * STR + 4 * G;
      float4 d = ld4(rowp);
      float4 a = (G > 0) ? ld4(rowp - 4) : d;
      float4 e = (G < NG - 1) ? ld4(rowp + 4) : d;
      if (PASS != 0) {
        if (supp & 0x001u) a.x = 0.f;
        if (supp & 0x002u) a.y = 0.f;
        if (supp & 0x004u) a.z = 0.f;
        if (supp & 0x008u) a.w = 0.f;
        if (supp & 0x010u) d.x = 0.f;
        if (supp & 0x020u) d.y = 0.f;
        if (supp & 0x040u) d.z = 0.f;
        if (supp & 0x080u) d.w = 0.f;
        if (supp & 0x100u) e.x = 0.f;
        if (supp & 0x200u) e.y = 0.f;
        if (supp & 0x400u) e.z = 0.f;
        if (supp & 0x800u) e.w = 0.f;
      }
      float4 hm;
      hm.x = max5(a.z, a.w, d.x, d.y, d.z);
      hm.y = max5(a.w, d.x, d.y, d.z, d.w);
      hm.z = max5(d.x, d.y, d.z, d.w, e.x);
      hm.w = max5(d.y, d.z, d.w, e.x, e.y);
      hw[ks % 5] = hm;
      cw[ks % 5] = d;
      snr[ks % 5] = (supp >> 4) & 0xFu;
      if (ks >= 4) {
        const int rq = r0 - 4 + ks;
        const int gy = y0 - 12 + rq;
        float4 vm;
        vm.x = max5(hw[0].x, hw[1].x, hw[2].x, hw[3].x, hw[4].x);
        vm.y = max5(hw[0].y, hw[1].y, hw[2].y, hw[3].y, hw[4].y);
        vm.z = max5(hw[0].z, hw[1].z, hw[2].z, hw[3].z, hw[4].z);
        vm.w = max5(hw[0].w, hw[1].w, hw[2].w, hw[3].w, hw[4].w);
        float4 c = cw[(ks + 3) % 5];
        uint32_t nm = (uint32_t)(c.x == vm.x) | ((uint32_t)(c.y == vm.y) << 1) |
                      ((uint32_t)(c.z == vm.z) << 2) | ((uint32_t)(c.w == vm.w) << 3);
        nm &= ((unsigned)gy < (unsigned)H) ? colm : 0u;
        const int widx = rq * MW + (G >> 3);
        const int shift = 4 * (G & 7);
        if (PASS == 0) {
          if (nm) atomicOr(&MOUT[widx], nm << shift);
        } else if (PASS == 1) {
          uint32_t fin = cnb[ks % 5] | (nm & ~snr[(ks + 3) % 5]);
          if (fin) atomicOr(&MOUT[widx], fin << shift);
        } else {
          uint32_t fin = cnb[ks % 5] | (nm & ~snr[(ks + 3) % 5]);
          if (fin && G >= 3 && G < 19 && rq >= 12 && rq < 76 && gy >= 2 && gy < H - 2) {
#pragma unroll
            for (int j = 0; j < 4; ++j) {
              if ((fin >> j) & 1u) {
                int gx = gx0 + j;
                if (gx >= 2 && gx < W - 2) {
                  float sval = S[rq * STR + 4 * G + j];
                  if (sval > 0.0f) {
                    uint32_t bits = __float_as_uint(sval);
                    uint32_t flat = (uint32_t)(gy * W + gx);
                    uint64_t key = ((uint64_t)bits << 32) | (uint64_t)(0xFFFFFFFFu - flat);
                    uint32_t pos = atomicAdd(cnt_loc, 1u);
                    if (pos < (uint32_t)LIST_CAP) {
                      list[pos] = key;
                    } else {
                      uint32_t pp = atomicAdd(&cand_count[b], 1u);
                      if (pp < (uint32_t)CAND_CAP) cand[(size_t)b * CAND_CAP + pp] = key;
                    }
                  }
                }
              }
            }
          }
        }
      }
    }
  }
}

// =============== the whole pipeline as ONE cooperative kernel ========================
// Round-8 lesson: 7 stream ops cost ~80us in dispatch gaps (~12us/op) while kernel
// work sums to ~117us. All phases are grid-stride (any grid size works); grid is
// occupancy-clamped host-side. grid.sync() + explicit __threadfence() on both sides
// (agent-scope wbL2/inv) handles cross-XCD visibility of plain stores (per-XCD L2s
// can hold stale clean lines of data another XCD updated).
__global__ void __launch_bounds__(256, 4) k_all(const float* __restrict__ scores,
                                                float* __restrict__ out,
                                                char* __restrict__ ws) {
  uint32_t* cnt = (uint32_t*)(ws + OFF_CNT);
  uint32_t* cand_count = cnt;                    // [B]
  uint32_t* sel_count  = cnt + 8;                // [B]
  uint32_t* gehist = (uint32_t*)(ws + OFF_EH);   // [B][256]
  uint32_t* gfhist = (uint32_t*)(ws + OFF_FH);   // [B][256]
  uint32_t* rankg  = (uint32_t*)(ws + OFF_RANK); // [B][SEL_CAP]
  uint64_t* sel    = (uint64_t*)(ws + OFF_SEL);
  uint64_t* cand   = (uint64_t*)(ws + OFF_CAND);

  __shared__ __align__(16) char smem[SMEM_BYTES];
  __shared__ uint32_t s_cnt, s_base;
  __shared__ int s_E;
  __shared__ uint64_t s_thr;

  cg::grid_group grid = cg::this_grid();
  const int tid = threadIdx.x;

  // ---- phase Z: zero counters + hist pages (replaces hipMemsetAsync) ----
  for (uint32_t i = blockIdx.x * 256u + tid; i < (uint32_t)(OFF_RANK / 4);
       i += gridDim.x * 256u)
    ((uint32_t*)ws)[i] = 0u;
  __threadfence();
  grid.sync();
  __threadfence();

  // ---- phase NMS: 2048 tiles, grid-stride ----
  {
    float* S = (float*)smem;
    uint32_t* M0s = (uint32_t*)(smem + 32384);
    uint32_t* M1s = M0s + RROWS * MW;
    uint64_t* list = (uint64_t*)(smem + 32384 + 2 * (RROWS * MW) * 4);  // 36064, 8-aligned
    for (uint32_t tile = blockIdx.x; tile < (uint32_t)(B * 256); tile += gridDim.x) {
      const int b = tile >> 8;
      const int x0 = (int)(tile & 15u) * 64;
      const int y0 = (int)((tile >> 4) & 15u) * 64;
      const float* img = scores + (size_t)b * H * W;
      if (tid == 0) s_cnt = 0;
      for (int u = tid; u < RROWS * NG; u += 256) {
        int r = u / NG, G = u % NG;
        int gy = y0 - 12 + r, gx = x0 - 12 + 4 * G;
        float4 v;
        if ((unsigned)gy < (unsigned)H && (unsigned)gx < (unsigned)W)
          v = ld4(img + (size_t)gy * W + gx);
        else
          v = make_float4(-INFINITY, -INFINITY, -INFINITY, -INFINITY);
        *reinterpret_cast<float4*>(&S[r * STR + 4 * G]) = v;
      }
      for (int i = tid; i < RROWS * MW; i += 256) {
        M0s[i] = 0;
        M1s[i] = 0;
      }
      __syncthreads();
      if (tid < NUNIT)
        score_pass<0>(tid, x0, y0, S, nullptr, M0s, nullptr, nullptr, nullptr, nullptr, b);
      __syncthreads();
      if (tid < NUNIT)
        score_pass<1>(tid, x0, y0, S, M0s, M1s, nullptr, nullptr, nullptr, nullptr, b);
      __syncthreads();
      if (tid < NUNIT)
        score_pass<2>(tid, x0, y0, S, M1s, nullptr, list, &s_cnt, cand, cand_count, b);
      __syncthreads();
      uint32_t nblk = s_cnt;
      uint32_t nmain = nblk < (uint32_t)LIST_CAP ? nblk : (uint32_t)LIST_CAP;
      if (tid == 0) s_base = atomicAdd(&cand_count[b], nmain);
      __syncthreads();
      uint32_t bg = s_base;
      for (uint32_t i = tid; i < nmain; i += 256) {
        uint32_t pp = bg + i;
        if (pp < (uint32_t)CAND_CAP) cand[(size_t)b * CAND_CAP + pp] = list[i];
      }
      __syncthreads();  // protect smem reuse for next tile
    }
  }
  __threadfence();
  grid.sync();
  __threadfence();

  // ---- phase A: exponent histogram (bucket = key>>55) ----
  {
    uint32_t* eh = (uint32_t*)smem;
    for (uint32_t bs = blockIdx.x; bs < (uint32_t)(B * NSL); bs += gridDim.x) {
      const int b = (int)(bs / NSL), sub = (int)(bs % NSL);
      uint32_t n = cand_count[b];
      if (n > (uint32_t)CAND_CAP) n = CAND_CAP;
      __syncthreads();  // smem reuse guard across bs iterations
      eh[tid] = 0;
      __syncthreads();
      const uint64_t* cb = cand + (size_t)b * CAND_CAP;
      for (uint32_t i = (uint32_t)sub * 256u + tid; i < n; i += (uint32_t)NSL * 256u)
        atomicAdd(&eh[(uint32_t)(cb[i] >> 55)], 1u);
      __syncthreads();
      uint32_t v = eh[tid];
      if (v) atomicAdd(&gehist[b * 256 + tid], v);
    }
  }
  __threadfence();
  grid.sync();
  __threadfence();

  // ---- phase B: fine histogram within crossing exponent E ----
  {
    uint32_t* fh = (uint32_t*)smem;
    uint32_t* ehl = fh + 256;
    for (uint32_t bs = blockIdx.x; bs < (uint32_t)(B * NSL); bs += gridDim.x) {
      const int b = (int)(bs / NSL), sub = (int)(bs % NSL);
      uint32_t n = cand_count[b];
      if (n > (uint32_t)CAND_CAP) n = CAND_CAP;
      __syncthreads();
      fh[tid] = 0;
      ehl[tid] = gehist[b * 256 + tid];
      __syncthreads();
      if (tid == 0) {
        uint32_t run = 0;
        int E = -1;
        for (int e = 255; e >= 0; --e) {
          uint32_t nrun = run + ehl[e];
          if (run < (uint32_t)TOPK && nrun >= (uint32_t)TOPK) E = e;
          run = nrun;
        }
        if (run < (uint32_t)TOPK) E = -1;  // fewer than TOPK: select all
        s_E = E;
      }
      __syncthreads();
      const int E = s_E;
      if (E >= 0) {  // block-uniform
        const uint64_t* cb = cand + (size_t)b * CAND_CAP;
        for (uint32_t i = (uint32_t)sub * 256u + tid; i < n; i += (uint32_t)NSL * 256u) {
          uint64_t key = cb[i];
          if ((uint32_t)(key >> 55) == (uint32_t)E)
            atomicAdd(&fh[(uint32_t)(key >> 47) & 0xFFu], 1u);
        }
      }
      __syncthreads();
      uint32_t v = fh[tid];
      if (v) atomicAdd(&gfhist[b * 256 + tid], v);
    }
  }
  __threadfence();
  grid.sync();
  __threadfence();

  // ---- phase C: threshold (suffix scans) + compact (wave-aggregated) + rankg zero ----
  {
    uint32_t* ehl = (uint32_t*)smem;
    uint32_t* fhl = ehl + 256;
    const int lane = tid & 63;
    for (uint32_t bs = blockIdx.x; bs < (uint32_t)(B * NSL); bs += gridDim.x) {
      const int b = (int)(bs / NSL), sub = (int)(bs % NSL);
      uint32_t n = cand_count[b];
      if (n > (uint32_t)CAND_CAP) n = CAND_CAP;
      __syncthreads();
      ehl[tid] = gehist[b * 256 + tid];
      fhl[tid] = gfhist[b * 256 + tid];
      if (tid == 0) {
        s_E = -1;
        s_thr = 0ull;
      }
      __syncthreads();
      for (int d = 1; d < 256; d <<= 1) {
        uint32_t ve = (tid + d < 256) ? ehl[tid + d] : 0u;
        uint32_t vf = (tid + d < 256) ? fhl[tid + d] : 0u;
        __syncthreads();
        ehl[tid] += ve;
        fhl[tid] += vf;
        __syncthreads();
      }
      {
        uint32_t nxt = (tid < 255) ? ehl[tid + 1] : 0u;
        if (ehl[tid] >= (uint32_t)TOPK && nxt < (uint32_t)TOPK) {
          s_E = tid;
          s_base = nxt;  // count with exponent > E
        }
      }
      __syncthreads();
      if (s_E >= 0) {
        uint32_t above = s_base;
        uint32_t Fn = (tid < 255) ? fhl[tid + 1] : 0u;
        if (above + fhl[tid] >= (uint32_t)TOPK && above + Fn < (uint32_t)TOPK)
          s_thr = ((uint64_t)(((uint32_t)s_E << 8) | (uint32_t)tid)) << 47;
      }
      __syncthreads();
      const uint64_t thr = s_thr;  // 0 => select all
      const uint64_t* cb = cand + (size_t)b * CAND_CAP;
      for (uint32_t i = (uint32_t)sub * 256u + tid; i < n; i += (uint32_t)NSL * 256u) {
        uint64_t key = cb[i];
        bool keep = key >= thr;
        uint64_t m = __ballot(keep);
        if (keep) {
          uint32_t cntw = (uint32_t)__popcll((unsigned long long)m);
          uint32_t pre =
              (uint32_t)__popcll((unsigned long long)(m & ((1ull << lane) - 1ull)));
          int leader = __ffsll((unsigned long long)m) - 1;
          uint32_t basew = 0;
          if (lane == leader) basew = atomicAdd(&sel_count[b], cntw);
          basew = __shfl(basew, leader);
          uint32_t pp = basew + pre;
          if (pp < (uint32_t)SEL_CAP) {
            sel[(size_t)b * SEL_CAP + pp] = key;
            rankg[(size_t)b * SEL_CAP + pp] = 0u;
          }
        }
      }
    }
  }
  __threadfence();
  grid.sync();
  __threadfence();

  // ---- phase D: rank = #{keys > me} (me-tile x chunk units, keys staged in LDS) ----
  {
    uint64_t* keys = (uint64_t*)smem;  // 8 KiB
    constexpr uint32_t NME = SEL_CAP / 256;    // 64
    constexpr uint32_t NCH = SEL_CAP / 1024;   // 16
    constexpr uint32_t UNITS = NME * NCH;      // 1024 per batch
    for (uint32_t u = blockIdx.x; u < (uint32_t)B * UNITS; u += gridDim.x) {
      const int b = (int)(u / UNITS);
      const uint32_t rem = u % UNITS;
      const uint32_t me0 = (rem & (NME - 1)) * 256u;
      const uint32_t c0 = (rem / NME) * 1024u;
      uint32_t n = sel_count[b];
      if (n > (uint32_t)SEL_CAP) n = SEL_CAP;
      if (me0 >= n || c0 >= n) continue;  // uniform per block
      const uint64_t* sb = sel + (size_t)b * SEL_CAP;
      uint32_t clen = n - c0;
      if (clen > 1024u) clen = 1024u;
      __syncthreads();  // protect keys from previous unit
      for (uint32_t i = tid; i < clen; i += 256u) keys[i] = sb[c0 + i];
      __syncthreads();
      const uint32_t me = me0 + tid;
      if (me < n) {
        const uint64_t kme = sb[me];
        uint32_t rank = 0;
        uint32_t i = 0;
        for (; i + 8 <= clen; i += 8) {
          rank += (keys[i] > kme);
          rank += (keys[i + 1] > kme);
          rank += (keys[i + 2] > kme);
          rank += (keys[i + 3] > kme);
          rank += (keys[i + 4] > kme);
          rank += (keys[i + 5] > kme);
          rank += (keys[i + 6] > kme);
          rank += (keys[i + 7] > kme);
        }
        for (; i < clen; ++i) rank += (keys[i] > kme);
        if (rank) atomicAdd(&rankg[(size_t)b * SEL_CAP + me], rank);
      }
    }
  }
  __threadfence();
  grid.sync();
  __threadfence();

  // ---- phase E: refine + scatter (8 lanes per sel item, write at row = rank) ----
  {
    const uint32_t TOTG = (uint32_t)B * SEL_CAP;
    const int ln = tid & 7;
    for (uint32_t g = blockIdx.x * 32u + (uint32_t)(tid >> 3); g < TOTG;
         g += gridDim.x * 32u) {
      const int b = (int)(g / SEL_CAP);
      const uint32_t i = g % SEL_CAP;
      uint32_t n = sel_count[b];
      if (n > (uint32_t)SEL_CAP) n = SEL_CAP;
      if (i >= n) continue;  // uniform across the 8-lane group
      uint32_t r = rankg[(size_t)b * SEL_CAP + i];
      if (r >= (uint32_t)TOPK) continue;  // uniform across the group
      uint64_t key = sel[(size_t)b * SEL_CAP + i];
      uint32_t flat = 0xFFFFFFFFu - (uint32_t)(key & 0xFFFFFFFFull);
      if (flat >= (uint32_t)(H * W)) flat = 0;
      const int ix = (int)(flat % W);
      const int iy = (int)(flat / W);
      const float* img = scores + (size_t)b * H * W;

      const int nt = (ln == 0) ? 4 : 3;
      float v[4];
      float mymax = -INFINITY;
#pragma unroll
      for (int q = 0; q < 4; ++q) {
        if (q < nt) {
          int t = ln + 8 * q;
          int y = iy + t / 5 - 2, x = ix + t % 5 - 2;
          float val = ((unsigned)x < (unsigned)W && (unsigned)y < (unsigned)H)
                          ? img[(size_t)y * W + x] : 0.0f;
          v[q] = val;
          mymax = fmaxf(mymax, val);
        }
      }
#pragma unroll
      for (int m = 1; m < 8; m <<= 1) mymax = fmaxf(mymax, __shfl_xor(mymax, m));
      float e[4];
      float sum = 0.f, sx = 0.f, sy = 0.f;
#pragma unroll
      for (int q = 0; q < 4; ++q) {
        if (q < nt) {
          int t = ln + 8 * q;
          float ev = expf((v[q] - mymax) / 0.1f);
          e[q] = ev;
          sum += ev;
          sx += ev * (float)(t % 5 - 2);
          sy += ev * (float)(t / 5 - 2);
        }
      }
#pragma unroll
      for (int m = 1; m < 8; m <<= 1) {
        sum += __shfl_xor(sum, m);
        sx += __shfl_xor(sx, m);
        sy += __shfl_xor(sy, m);
      }
      float rx = sx / sum, ry = sy / sum;
      float dsp = 0.f;
#pragma unroll
      for (int q = 0; q < 4; ++q) {
        if (q < nt) {
          int t = ln + 8 * q;
          float dx = ((float)(t % 5 - 2) - rx) * 0.5f;
          float dy = ((float)(t / 5 - 2) - ry) * 0.5f;
          dsp += e[q] * (dx * dx + dy * dy);
        }
      }
#pragma unroll
      for (int m = 1; m < 8; m <<= 1) dsp += __shfl_xor(dsp, m);
      if (ln == 0) {
        dsp /= sum;
        float kx = ((float)ix + rx) / 1023.0f * 2.0f - 1.0f;
        float ky = ((float)iy + ry) / 1023.0f * 2.0f - 1.0f;
        float px = (kx + 1.0f) * 0.5f * 1023.0f;
        float py = (ky + 1.0f) * 0.5f * 1023.0f;
        float x0f = floorf(px), y0f = floorf(py);
        float wx1 = px - x0f, wx0 = 1.0f - wx1;
        float wy1 = py - y0f, wy0 = 1.0f - wy1;
        int x0 = (int)x0f, y0 = (int)y0f;
        float sc = 0.0f;
        int xs[2] = {x0, x0 + 1};
        int ys[2] = {y0, y0 + 1};
        float wxs[2] = {wx0, wx1};
        float wys[2] = {wy0, wy1};
#pragma unroll
        for (int yy = 0; yy < 2; ++yy)
#pragma unroll
          for (int xx = 0; xx < 2; ++xx) {
            int xi = xs[xx], yi = ys[yy];
            bool valid = (xi >= 0 && xi < W && yi >= 0 && yi < H);
            int xc = min(max(xi, 0), W - 1);
            int yc = min(max(yi, 0), H - 1);
            float vv = valid ? img[(size_t)yc * W + xc] : 0.0f;
            sc += vv * (wxs[xx] * wys[yy]);
          }
        out[((size_t)b * TOPK + r) * 2 + 0] = kx;
        out[((size_t)b * TOPK + r) * 2 + 1] = ky;
        out[(size_t)B * TOPK * 2 + (size_t)b * TOPK + r] = sc;
        out[(size_t)B * TOPK * 3 + (size_t)b * TOPK + r] = dsp;
      }
    }
  }
}

}  // namespace

extern "C" void kernel_launch(void* const* d_in, const int* in_sizes, int n_in,
                              void* d_out, int out_size, void* d_ws, size_t ws_size,
                              hipStream_t stream) {
  const float* scores = (const float*)d_in[0];
  float* out = (float*)d_out;
  char* ws = (char*)d_ws;

  // occupancy-clamped cooperative grid (cached; host query, no stream op)
  static int gblocks = 0;
  if (gblocks == 0) {
    int occ = 0;
    (void)hipOccupancyMaxActiveBlocksPerMultiprocessor(&occ, (const void*)k_all, 256, 0);
    if (occ < 1) occ = 1;
    long cap = (long)occ * 256;  // 256 CUs on MI355X
    gblocks = (int)(cap < 1024 ? cap : 1024);
  }

  void* args[] = {(void*)&scores, (void*)&out, (void*)&ws};
  (void)hipLaunchCooperativeKernel((const void*)k_all, dim3(gblocks), dim3(256), args,
                                   0, stream);
}

// Round 11
// 197.440 us; speedup vs baseline: 5.8242x; 5.8242x over previous
//
#include <hip/hip_runtime.h>
#include <stdint.h>

// NOTE: functionally identical to the round-10 submission. That bench died with
// "MI355X container failed twice" — a broker/provisioning-stage failure signature
// (no pytest output, no profile), distinct from round 6's post-run core dump which
// an identical resubmission cleared. Full audit of the delta vs the round-8 PASS
// found no fault path (tail hist indexes are in-bounds, M0s reuse is behind the
// pass-2 barrier, no divergent barriers, LDS unchanged at 38912B). Re-running the
// identical experiment per the rigor discipline; if it fails again with the same
// signature, revert to the byte-exact round-8 kernel.

namespace {

constexpr int B = 8;
constexpr int H = 1024;
constexpr int W = 1024;
constexpr int TOPK = 4096;
constexpr int CAND_CAP = 131072;  // per batch
constexpr int SEL_CAP = 16384;    // per batch
constexpr int LIST_CAP = 320;     // per 64x64 tile
constexpr int NHB = 32;           // fhist slice blocks per batch

// fused-NMS tile: 64x64 interior, radius-12 staged halo.
// Validity chain (3 fused stages): M0 mask valid rows [2,89]/cols [2,86);
// M1 (cumulative after iter1) valid rows [4,87]/cols [4,84); final emission
// valid rows [6,85]/cols [6,82) => interior rows/cols 12..75 fully covered.
constexpr int RROWS = 92;   // staged score rows
constexpr int NG = 22;      // float4 col-groups (88 cols)
constexpr int STR = 88;     // score row stride (floats)
constexpr int MW = 5;       // mask words/row (bank-conflict pad, r8: 5.06M->3.97M)
constexpr int NSTRIP = 11;  // 11 strips x 8 output rows = rows 2..89
constexpr int NUNIT = NG * NSTRIP;  // 242 <= 256

// rank kernel tiling (round-5 lesson: 2D (me,chunk) split keeps ~680 blocks active)
constexpr int RK_ME = 256;   // me-keys per block (1/thread)
constexpr int RK_CH = 1024;  // chunk keys staged in LDS per block

// workspace layout (bytes).
// Round-9 lesson: cooperative grid.sync on 8-XCD MI355X costs ~200us/sync (system-
// scope arrival counter + per-XCD L2 flush) — kernel boundaries are CHEAPER than
// grid syncs here. Structure stays multi-kernel; launch count trimmed by folding
// the exponent hist into k_nms's tail (candidates already in LDS, sparse merge).
constexpr size_t OFF_CNT   = 0;                                   // 4 KiB
constexpr size_t OFF_EH    = 4096;                                // B*256*4 = 8 KiB
constexpr size_t OFF_FH    = OFF_EH + (size_t)B * 256 * 4;        // 8 KiB
constexpr size_t OFF_RANK  = OFF_FH + (size_t)B * 256 * 4;        // B*SEL_CAP*4 = 512 KiB
constexpr size_t OFF_SEL   = OFF_RANK + (size_t)B * SEL_CAP * 4;  // 1 MiB
constexpr size_t OFF_CAND  = OFF_SEL + (size_t)B * SEL_CAP * 8;   // 8 MiB
constexpr size_t MEMSET_BYTES = OFF_RANK;  // cnt + hist pages only (20.5 KiB)

__device__ __forceinline__ float max5(float a, float b, float c, float d, float e) {
  return fmaxf(fmaxf(fmaxf(a, b), fmaxf(c, d)), e);
}
__device__ __forceinline__ float4 ld4(const float* p) {
  return *reinterpret_cast<const float4*>(p);
}

// One unit: col-group G in [0,22), strip s in [0,11) -> emission rows r0..r0+7
// (r0 = 2+8s). PASS 0: plain local-max -> M0. PASS 1/2: inline dilation of the
// previous mask via a 2-row-lookahead ring. PASS 1 writes cumulative mask M1.
// PASS 2 emits candidates into the LDS list (exp-hist of overflow keys goes
// straight to gehist — rare).
template <int PASS>
__device__ __forceinline__ void score_pass(
    int u, int x0, int y0, const float* __restrict__ S,
    const uint32_t* __restrict__ MIN_, uint32_t* __restrict__ MOUT,
    uint64_t* list, uint32_t* cnt_loc, uint64_t* cand, uint32_t* cand_count,
    uint32_t* __restrict__ gehist, int b) {
  const int G = u % NG, s = u / NG;
  const int r0 = 2 + 8 * s;
  const int gx0 = x0 - 12 + 4 * G;
  uint32_t colm = 0;
#pragma unroll
  for (int j = 0; j < 4; ++j)
    if ((unsigned)(gx0 + j) < (unsigned)W) colm |= 1u << j;

  // 16-col mask window starting at p2 = 4G-6 (covers 5-wide OR for 12 score cols)
  const int p2 = 4 * G - 6;
  const int pw2 = (p2 < 0) ? 0 : (p2 >> 5);
  const int psh2 = (p2 < 0) ? 0 : (p2 & 31);
  const int pls2 = (p2 < 0) ? -p2 : 0;

  float4 hw[5], cw[5];
  uint32_t snr[5], mor[5], cnb[5];
  constexpr int NK = (PASS == 0) ? 12 : 16;
#pragma unroll
  for (int k = 0; k < NK; ++k) {
    if (PASS != 0) {
      const int mr = r0 - 4 + k;
      uint32_t morrow = 0, cnib = 0;
      if ((unsigned)mr < (unsigned)RROWS) {
        const uint32_t* srow = MIN_ + mr * MW;
        uint64_t X = (uint64_t)srow[pw2] | ((uint64_t)srow[pw2 + 1] << 32);
        uint64_t win = pls2 ? (X << pls2) : (X >> psh2);
        uint64_t t5 = win | (win >> 1) | (win >> 2) | (win >> 3) | (win >> 4);
        morrow = (uint32_t)t5 & 0xFFFu;
        cnib = (uint32_t)(win >> 6) & 0xFu;
      }
      mor[k % 5] = morrow;
      cnb[k % 5] = cnib;
    }
    const int ks = (PASS == 0) ? k : k - 4;
    if (ks >= 0) {
      const int sr = r0 - 2 + ks;
      uint32_t supp = 0;
      if (PASS != 0) supp = mor[0] | mor[1] | mor[2] | mor[3] | mor[4];
      const float* rowp = S + sr * STR + 4 * G;
      float4 d = ld4(rowp);
      float4 a = (G > 0) ? ld4(rowp - 4) : d;  // garbage-only cols, safe
      float4 e = (G < NG - 1) ? ld4(rowp + 4) : d;
      if (PASS != 0) {
        if (supp & 0x001u) a.x = 0.f;
        if (supp & 0x002u) a.y = 0.f;
        if (supp & 0x004u) a.z = 0.f;
        if (supp & 0x008u) a.w = 0.f;
        if (supp & 0x010u) d.x = 0.f;
        if (supp & 0x020u) d.y = 0.f;
        if (supp & 0x040u) d.z = 0.f;
        if (supp & 0x080u) d.w = 0.f;
        if (supp & 0x100u) e.x = 0.f;
        if (supp & 0x200u) e.y = 0.f;
        if (supp & 0x400u) e.z = 0.f;
        if (supp & 0x800u) e.w = 0.f;
      }
      float4 hm;
      hm.x = max5(a.z, a.w, d.x, d.y, d.z);
      hm.y = max5(a.w, d.x, d.y, d.z, d.w);
      hm.z = max5(d.x, d.y, d.z, d.w, e.x);
      hm.w = max5(d.y, d.z, d.w, e.x, e.y);
      hw[ks % 5] = hm;
      cw[ks % 5] = d;
      snr[ks % 5] = (supp >> 4) & 0xFu;
      if (ks >= 4) {
        const int rq = r0 - 4 + ks;  // emission row
        const int gy = y0 - 12 + rq;
        float4 vm;
        vm.x = max5(hw[0].x, hw[1].x, hw[2].x, hw[3].x, hw[4].x);
        vm.y = max5(hw[0].y, hw[1].y, hw[2].y, hw[3].y, hw[4].y);
        vm.z = max5(hw[0].z, hw[1].z, hw[2].z, hw[3].z, hw[4].z);
        vm.w = max5(hw[0].w, hw[1].w, hw[2].w, hw[3].w, hw[4].w);
        float4 c = cw[(ks + 3) % 5];  // center (masked for PASS 1/2)
        uint32_t nm = (uint32_t)(c.x == vm.x) | ((uint32_t)(c.y == vm.y) << 1) |
                      ((uint32_t)(c.z == vm.z) << 2) | ((uint32_t)(c.w == vm.w) << 3);
        nm &= ((unsigned)gy < (unsigned)H) ? colm : 0u;
        const int widx = rq * MW + (G >> 3);
        const int shift = 4 * (G & 7);
        if (PASS == 0) {
          if (nm) atomicOr(&MOUT[widx], nm << shift);
        } else if (PASS == 1) {
          uint32_t fin = cnb[ks % 5] | (nm & ~snr[(ks + 3) % 5]);
          if (fin) atomicOr(&MOUT[widx], fin << shift);
        } else {
          uint32_t fin = cnb[ks % 5] | (nm & ~snr[(ks + 3) % 5]);
          if (fin && G >= 3 && G < 19 && rq >= 12 && rq < 76 && gy >= 2 && gy < H - 2) {
#pragma unroll
            for (int j = 0; j < 4; ++j) {
              if ((fin >> j) & 1u) {
                int gx = gx0 + j;
                if (gx >= 2 && gx < W - 2) {
                  float sval = S[rq * STR + 4 * G + j];  // original (unmasked) score
                  if (sval > 0.0f) {
                    uint32_t bits = __float_as_uint(sval);
                    uint32_t flat = (uint32_t)(gy * W + gx);
                    uint64_t key = ((uint64_t)bits << 32) | (uint64_t)(0xFFFFFFFFu - flat);
                    uint32_t pos = atomicAdd(cnt_loc, 1u);
                    if (pos < (uint32_t)LIST_CAP) {
                      list[pos] = key;
                    } else {  // tie overflow: direct global append + exp hist (rare)
                      uint32_t pp = atomicAdd(&cand_count[b], 1u);
                      if (pp < (uint32_t)CAND_CAP) cand[(size_t)b * CAND_CAP + pp] = key;
                      atomicAdd(&gehist[(size_t)b * 256 + (bits >> 23)], 1u);
                    }
                  }
                }
              }
            }
          }
        }
      }
    }
  }
}

// ---------------- fused 3-pass NMS + candidate emit + exp-hist tail ------------------
__global__ void __launch_bounds__(256, 4) k_nms(const float* __restrict__ scores,
                                                uint64_t* __restrict__ cand,
                                                uint32_t* __restrict__ cand_count,
                                                uint32_t* __restrict__ gehist) {
  __shared__ float S[RROWS * STR];
  __shared__ uint32_t M0s[RROWS * MW];
  __shared__ uint32_t M1s[RROWS * MW];
  __shared__ uint64_t list[LIST_CAP];
  __shared__ uint32_t cnt_loc, base_g;
  const int b = blockIdx.z;
  const int x0 = blockIdx.x * 64, y0 = blockIdx.y * 64;
  const int tid = threadIdx.x;
  const float* img = scores + (size_t)b * H * W;
  if (tid == 0) cnt_loc = 0;

  for (int u = tid; u < RROWS * NG; u += 256) {
    int r = u / NG, G = u % NG;
    int gy = y0 - 12 + r, gx = x0 - 12 + 4 * G;
    float4 v;
    if ((unsigned)gy < (unsigned)H && (unsigned)gx < (unsigned)W)
      v = ld4(img + (size_t)gy * W + gx);
    else
      v = make_float4(-INFINITY, -INFINITY, -INFINITY, -INFINITY);
    *reinterpret_cast<float4*>(&S[r * STR + 4 * G]) = v;
  }
  for (int i = tid; i < RROWS * MW; i += 256) {
    M0s[i] = 0;
    M1s[i] = 0;
  }
  __syncthreads();
  if (tid < NUNIT)
    score_pass<0>(tid, x0, y0, S, nullptr, M0s, nullptr, nullptr, nullptr, nullptr,
                  nullptr, b);
  __syncthreads();
  if (tid < NUNIT)
    score_pass<1>(tid, x0, y0, S, M0s, M1s, nullptr, nullptr, nullptr, nullptr,
                  nullptr, b);
  __syncthreads();
  if (tid < NUNIT)
    score_pass<2>(tid, x0, y0, S, M1s, nullptr, list, &cnt_loc, cand, cand_count,
                  gehist, b);
  __syncthreads();
  uint32_t nblk = cnt_loc;
  uint32_t nmain = nblk < (uint32_t)LIST_CAP ? nblk : (uint32_t)LIST_CAP;
  if (tid == 0) base_g = atomicAdd(&cand_count[b], nmain);
  M0s[tid] = 0;  // reuse M0s (dead after pass 1) as 256-bin exp hist
  __syncthreads();
  uint32_t bg = base_g;
  for (uint32_t i = tid; i < nmain; i += 256) {
    uint64_t key = list[i];
    uint32_t pp = bg + i;
    if (pp < (uint32_t)CAND_CAP) cand[(size_t)b * CAND_CAP + pp] = key;
    atomicAdd(&M0s[(uint32_t)(key >> 55)], 1u);  // exp bucket = score_bits>>23 (<=126)
  }
  __syncthreads();
  uint32_t v = M0s[tid];
  if (v) atomicAdd(&gehist[(size_t)b * 256 + tid], v);  // ~4-6 sparse bins per block
}

// ---------------- fine histogram within crossing exponent E --------------------------
// Each block independently recomputes E from gehist (1KB, L2-hit, parallel-redundant)
// then fine-byte histograms keys with exponent E. Sparse merge like the nms tail.
__global__ void __launch_bounds__(256) k_fhist(const uint64_t* __restrict__ cand,
                                               const uint32_t* __restrict__ cand_count,
                                               const uint32_t* __restrict__ gehist,
                                               uint32_t* __restrict__ gfhist) {
  __shared__ uint32_t fh[256];
  __shared__ uint32_t ehl[256];
  __shared__ int sE;
  const int b = blockIdx.y, t = threadIdx.x;
  uint32_t n = cand_count[b];
  if (n > (uint32_t)CAND_CAP) n = CAND_CAP;
  fh[t] = 0;
  ehl[t] = gehist[b * 256 + t];
  __syncthreads();
  if (t == 0) {
    uint32_t run = 0;
    int E = -1;
    for (int e = 255; e >= 0; --e) {
      uint32_t nrun = run + ehl[e];
      if (run < (uint32_t)TOPK && nrun >= (uint32_t)TOPK) E = e;
      run = nrun;
    }
    if (run < (uint32_t)TOPK) E = -1;  // fewer than TOPK candidates: select all
    sE = E;
  }
  __syncthreads();
  const int E = sE;
  if (E < 0) return;
  const uint64_t* cb = cand + (size_t)b * CAND_CAP;
  for (uint32_t i = blockIdx.x * 256 + t; i < n; i += NHB * 256) {
    uint64_t key = cb[i];
    if ((uint32_t)(key >> 55) == (uint32_t)E)
      atomicAdd(&fh[(uint32_t)(key >> 47) & 0xFFu], 1u);
  }
  __syncthreads();
  uint32_t v = fh[t];
  if (v) atomicAdd(&gfhist[b * 256 + t], v);
}

// ---------------- compact (threshold-find fused in) ----------------------------------
// Each block recomputes thr from gehist/gfhist with a parallel suffix-scan, then
// filters its 1024-candidate slice. Zeroes rankg[pp] for every sel slot written.
__global__ void __launch_bounds__(1024) k_compact(const uint64_t* __restrict__ cand,
                                                  const uint32_t* __restrict__ cand_count,
                                                  const uint32_t* __restrict__ gehist,
                                                  const uint32_t* __restrict__ gfhist,
                                                  uint64_t* __restrict__ sel,
                                                  uint32_t* __restrict__ sel_count,
                                                  uint32_t* __restrict__ rankg) {
  __shared__ uint64_t list[1024];
  __shared__ uint32_t cnt_loc, base_g;
  __shared__ uint32_t eh[256], fh[256];
  __shared__ int sE;
  __shared__ uint32_t sAbove;
  __shared__ uint64_t s_thr;
  const int b = blockIdx.y;
  uint32_t n = cand_count[b];
  if (n > (uint32_t)CAND_CAP) n = CAND_CAP;
  const int tid = threadIdx.x;
  if (tid == 0) {
    cnt_loc = 0;
    sE = -1;
    s_thr = 0ull;
  }
  if (tid < 256) {
    eh[tid] = gehist[b * 256 + tid];
    fh[tid] = gfhist[b * 256 + tid];
  }
  __syncthreads();
  for (int d = 1; d < 256; d <<= 1) {
    uint32_t ve = 0, vf = 0;
    if (tid < 256) {
      ve = (tid + d < 256) ? eh[tid + d] : 0u;
      vf = (tid + d < 256) ? fh[tid + d] : 0u;
    }
    __syncthreads();
    if (tid < 256) {
      eh[tid] += ve;
      fh[tid] += vf;
    }
    __syncthreads();
  }
  if (tid < 256) {
    uint32_t nxt = (tid < 255) ? eh[tid + 1] : 0u;
    if (eh[tid] >= (uint32_t)TOPK && nxt < (uint32_t)TOPK) {
      sE = tid;
      sAbove = nxt;  // count of keys with exponent > E (< TOPK by construction)
    }
  }
  __syncthreads();
  if (sE >= 0 && tid < 256) {
    uint32_t above = sAbove;
    uint32_t Fn = (tid < 255) ? fh[tid + 1] : 0u;
    if (above + fh[tid] >= (uint32_t)TOPK && above + Fn < (uint32_t)TOPK)
      s_thr = ((uint64_t)(((uint32_t)sE << 8) | (uint32_t)tid)) << 47;
  }
  __syncthreads();
  const uint64_t thr = s_thr;  // 0 => select all (fewer than TOPK candidates)
  uint32_t i = blockIdx.x * 1024 + tid;
  if (i < n) {
    uint64_t key = cand[(size_t)b * CAND_CAP + i];
    if (key >= thr) {
      uint32_t pos = atomicAdd(&cnt_loc, 1u);
      list[pos] = key;
    }
  }
  __syncthreads();
  uint32_t nblk = cnt_loc;
  if (tid == 0 && nblk > 0) base_g = atomicAdd(&sel_count[b], nblk);
  __syncthreads();
  if (nblk > 0 && (uint32_t)tid < nblk) {
    uint32_t pp = base_g + tid;
    if (pp < (uint32_t)SEL_CAP) {
      sel[(size_t)b * SEL_CAP + pp] = list[tid];
      rankg[(size_t)b * SEL_CAP + pp] = 0u;
    }
  }
}

// ---------------- tiled partial ranking ----------------------------------------------
__global__ void __launch_bounds__(RK_ME) k_rank_part(const uint64_t* __restrict__ sel,
                                                     const uint32_t* __restrict__ sel_count,
                                                     uint32_t* __restrict__ rankg) {
  __shared__ uint64_t keys[RK_CH];  // 8 KiB
  const int b = blockIdx.z;
  uint32_t n = sel_count[b];
  if (n > (uint32_t)SEL_CAP) n = SEL_CAP;
  const uint32_t me0 = blockIdx.x * RK_ME;
  const uint32_t c0 = blockIdx.y * RK_CH;
  if (me0 >= n || c0 >= n) return;
  const uint64_t* sb = sel + (size_t)b * SEL_CAP;
  uint32_t clen = n - c0;
  if (clen > (uint32_t)RK_CH) clen = RK_CH;
  for (uint32_t i = threadIdx.x; i < clen; i += RK_ME) keys[i] = sb[c0 + i];
  __syncthreads();
  const uint32_t me = me0 + threadIdx.x;
  if (me >= n) return;
  const uint64_t kme = sb[me];
  uint32_t rank = 0;
  uint32_t i = 0;
  for (; i + 8 <= clen; i += 8) {
    rank += (keys[i] > kme);
    rank += (keys[i + 1] > kme);
    rank += (keys[i + 2] > kme);
    rank += (keys[i + 3] > kme);
    rank += (keys[i + 4] > kme);
    rank += (keys[i + 5] > kme);
    rank += (keys[i + 6] > kme);
    rank += (keys[i + 7] > kme);
  }
  for (; i < clen; ++i) rank += (keys[i] > kme);
  if (rank) atomicAdd(&rankg[(size_t)b * SEL_CAP + me], rank);
}

// ---------------- refinement (scatter fused in): 8 lanes per sel item ----------------
__global__ void __launch_bounds__(256) k_refine(const float* __restrict__ scores,
                                                const uint64_t* __restrict__ sel,
                                                const uint32_t* __restrict__ sel_count,
                                                const uint32_t* __restrict__ rankg,
                                                float* __restrict__ out) {
  int gid = blockIdx.x * 256 + threadIdx.x;
  int idx = gid >> 3, ln = gid & 7;
  const int b = idx / SEL_CAP;
  const int i = idx % SEL_CAP;
  uint32_t n = sel_count[b];
  if (n > (uint32_t)SEL_CAP) n = SEL_CAP;
  if ((uint32_t)i >= n) return;  // uniform across the 8-lane group
  uint32_t r = rankg[(size_t)b * SEL_CAP + i];
  if (r >= (uint32_t)TOPK) return;  // uniform across the group
  uint64_t key = sel[(size_t)b * SEL_CAP + i];
  uint32_t flat = 0xFFFFFFFFu - (uint32_t)(key & 0xFFFFFFFFull);
  if (flat >= (uint32_t)(H * W)) flat = 0;  // safety guard
  const int ix = (int)(flat % W);
  const int iy = (int)(flat / W);
  const float* img = scores + (size_t)b * H * W;

  const int nt = (ln == 0) ? 4 : 3;
  float v[4];
  float mymax = -INFINITY;
#pragma unroll
  for (int q = 0; q < 4; ++q) {
    if (q < nt) {
      int t = ln + 8 * q;
      int y = iy + t / 5 - 2, x = ix + t % 5 - 2;
      float val = ((unsigned)x < (unsigned)W && (unsigned)y < (unsigned)H)
                      ? img[(size_t)y * W + x] : 0.0f;
      v[q] = val;
      mymax = fmaxf(mymax, val);
    }
  }
#pragma unroll
  for (int m = 1; m < 8; m <<= 1) mymax = fmaxf(mymax, __shfl_xor(mymax, m));
  float e[4];
  float sum = 0.f, sx = 0.f, sy = 0.f;
#pragma unroll
  for (int q = 0; q < 4; ++q) {
    if (q < nt) {
      int t = ln + 8 * q;
      float ev = expf((v[q] - mymax) / 0.1f);
      e[q] = ev;
      sum += ev;
      sx += ev * (float)(t % 5 - 2);
      sy += ev * (float)(t / 5 - 2);
    }
  }
#pragma unroll
  for (int m = 1; m < 8; m <<= 1) {
    sum += __shfl_xor(sum, m);
    sx += __shfl_xor(sx, m);
    sy += __shfl_xor(sy, m);
  }
  float rx = sx / sum, ry = sy / sum;
  float dsp = 0.f;
#pragma unroll
  for (int q = 0; q < 4; ++q) {
    if (q < nt) {
      int t = ln + 8 * q;
      float dx = ((float)(t % 5 - 2) - rx) * 0.5f;
      float dy = ((float)(t / 5 - 2) - ry) * 0.5f;
      dsp += e[q] * (dx * dx + dy * dy);
    }
  }
#pragma unroll
  for (int m = 1; m < 8; m <<= 1) dsp += __shfl_xor(dsp, m);
  if (ln != 0) return;
  dsp /= sum;
  float kx = ((float)ix + rx) / 1023.0f * 2.0f - 1.0f;
  float ky = ((float)iy + ry) / 1023.0f * 2.0f - 1.0f;
  float px = (kx + 1.0f) * 0.5f * 1023.0f;
  float py = (ky + 1.0f) * 0.5f * 1023.0f;
  float x0f = floorf(px), y0f = floorf(py);
  float wx1 = px - x0f, wx0 = 1.0f - wx1;
  float wy1 = py - y0f, wy0 = 1.0f - wy1;
  int x0 = (int)x0f, y0 = (int)y0f;
  float sc = 0.0f;
  {
    int xs[2] = {x0, x0 + 1};
    int ys[2] = {y0, y0 + 1};
    float wxs[2] = {wx0, wx1};
    float wys[2] = {wy0, wy1};
#pragma unroll
    for (int yy = 0; yy < 2; ++yy)
#pragma unroll
      for (int xx = 0; xx < 2; ++xx) {
        int xi = xs[xx], yi = ys[yy];
        bool valid = (xi >= 0 && xi < W && yi >= 0 && yi < H);
        int xc = min(max(xi, 0), W - 1);
        int yc = min(max(yi, 0), H - 1);
        float vv = valid ? img[(size_t)yc * W + xc] : 0.0f;
        sc += vv * (wxs[xx] * wys[yy]);
      }
  }
  out[((size_t)b * TOPK + r) * 2 + 0] = kx;
  out[((size_t)b * TOPK + r) * 2 + 1] = ky;
  out[(size_t)B * TOPK * 2 + (size_t)b * TOPK + r] = sc;
  out[(size_t)B * TOPK * 3 + (size_t)b * TOPK + r] = dsp;
}

}  // namespace

extern "C" void kernel_launch(void* const* d_in, const int* in_sizes, int n_in,
                              void* d_out, int out_size, void* d_ws, size_t ws_size,
                              hipStream_t stream) {
  const float* scores = (const float*)d_in[0];
  float* out = (float*)d_out;
  char* ws = (char*)d_ws;

  uint32_t* cnt = (uint32_t*)(ws + OFF_CNT);
  uint32_t* cand_count = cnt;                    // [B]
  uint32_t* sel_count  = cnt + 8;                // [B]
  uint32_t* gehist = (uint32_t*)(ws + OFF_EH);   // [B][256]
  uint32_t* gfhist = (uint32_t*)(ws + OFF_FH);   // [B][256]
  uint32_t* rankg = (uint32_t*)(ws + OFF_RANK);  // [B][SEL_CAP]
  uint64_t* sel  = (uint64_t*)(ws + OFF_SEL);
  uint64_t* cand = (uint64_t*)(ws + OFF_CAND);

  hipMemsetAsync(ws + OFF_CNT, 0, MEMSET_BYTES, stream);

  k_nms<<<dim3(W / 64, H / 64, B), 256, 0, stream>>>(scores, cand, cand_count, gehist);
  k_fhist<<<dim3(NHB, B), 256, 0, stream>>>(cand, cand_count, gehist, gfhist);
  k_compact<<<dim3(CAND_CAP / 1024, B), 1024, 0, stream>>>(cand, cand_count, gehist,
                                                           gfhist, sel, sel_count, rankg);
  k_rank_part<<<dim3(SEL_CAP / RK_ME, SEL_CAP / RK_CH, B), RK_ME, 0, stream>>>(
      sel, sel_count, rankg);
  k_refine<<<(B * SEL_CAP * 8) / 256, 256, 0, stream>>>(scores, sel, sel_count, rankg,
                                                        out);
}

// Round 12
// 195.866 us; speedup vs baseline: 5.8710x; 1.0080x over previous
//
#include <hip/hip_runtime.h>
#include <stdint.h>

namespace {

constexpr int B = 8;
constexpr int H = 1024;
constexpr int W = 1024;
constexpr int TOPK = 4096;
constexpr int CAND_CAP = 131072;  // per batch
constexpr int SEL_CAP = 16384;    // per batch
constexpr int LIST_CAP = 320;     // per 64x64 tile
constexpr int NHB = 32;           // fhist slice blocks per batch

// fused-NMS tile: 64x64 interior, radius-8 staged halo (round-12: the old halo-12
// was over-provisioned — chain needs only 6, rounded to 8 for float4 alignment).
// Validity chain: M0 computed rows [4,75] (valid: scores rows 2..77 staged);
// M1 computed rows [4,75] (needs M0 rows 2..77; rows <4/>75 read zeros, and those
// M1 rows are never consumed); emission rows [8,71] = gy in [y0, y0+63], consuming
// M1 rows 6..73 (computed+valid) and scores rows 6..73. Cols symmetric: interior
// cols 8..71, emission-valid cols [6,73].
constexpr int RROWS = 78;   // staged score rows (gy = y0-8+r)
constexpr int NG = 20;      // float4 col-groups (80 cols, gx0 = x0-8+4G)
constexpr int STR = 80;     // score row stride (floats)
constexpr int MW = 5;       // mask words/row (3 used for 80 cols + 2 zero pad;
                            // stride 5 keeps cross-strip reads off one bank, r8)
constexpr int NSM = 9;      // mask-pass strips: r0 = 4+8s -> rows 4..75
constexpr int NSE = 8;      // emission strips:  r0 = 8+8s -> rows 8..71
constexpr int NUNIT_M = NG * NSM;  // 180
constexpr int NUNIT_E = NG * NSE;  // 160
// LDS: S 24960 + masks 2*1560 + list 2560 + ~16 = ~30.6 KiB -> 5 blocks/CU.

// rank kernel tiling (round-5 lesson: 2D (me,chunk) split keeps ~680 blocks active)
constexpr int RK_ME = 256;   // me-keys per block (1/thread)
constexpr int RK_CH = 1024;  // chunk keys staged in LDS per block

// workspace layout (bytes).
// Round-9 lesson: cooperative grid.sync on 8-XCD MI355X costs ~200us/sync —
// kernel boundaries are CHEAPER than grid syncs; stay multi-kernel.
constexpr size_t OFF_CNT   = 0;                                   // 4 KiB
constexpr size_t OFF_EH    = 4096;                                // B*256*4 = 8 KiB
constexpr size_t OFF_FH    = OFF_EH + (size_t)B * 256 * 4;        // 8 KiB
constexpr size_t OFF_RANK  = OFF_FH + (size_t)B * 256 * 4;        // B*SEL_CAP*4 = 512 KiB
constexpr size_t OFF_SEL   = OFF_RANK + (size_t)B * SEL_CAP * 4;  // 1 MiB
constexpr size_t OFF_CAND  = OFF_SEL + (size_t)B * SEL_CAP * 8;   // 8 MiB
constexpr size_t MEMSET_BYTES = OFF_RANK;  // cnt + hist pages only (20.5 KiB)

__device__ __forceinline__ float max5(float a, float b, float c, float d, float e) {
  return fmaxf(fmaxf(fmaxf(a, b), fmaxf(c, d)), e);
}
__device__ __forceinline__ float4 ld4(const float* p) {
  return *reinterpret_cast<const float4*>(p);
}

// One unit: col-group G in [0,NG), strip s -> output rows r0..r0+7, where
// r0 = 4+8s for mask passes (0/1) and 8+8s for emission (2). PASS 0: plain
// local-max -> M0. PASS 1/2: inline dilation of the previous mask via a
// 2-row-lookahead ring. PASS 1 writes cumulative M1 = M0|new. PASS 2 emits
// candidates into the LDS list (overflow keys append+hist globally — rare).
template <int PASS>
__device__ __forceinline__ void score_pass(
    int u, int x0, int y0, const float* __restrict__ S,
    const uint32_t* __restrict__ MIN_, uint32_t* __restrict__ MOUT,
    uint64_t* list, uint32_t* cnt_loc, uint64_t* cand, uint32_t* cand_count,
    uint32_t* __restrict__ gehist, int b) {
  const int G = u % NG, s = u / NG;
  const int r0 = ((PASS == 2) ? 8 : 4) + 8 * s;
  const int gx0 = x0 - 8 + 4 * G;
  uint32_t colm = 0;
#pragma unroll
  for (int j = 0; j < 4; ++j)
    if ((unsigned)(gx0 + j) < (unsigned)W) colm |= 1u << j;

  // 16-col mask window starting at p2 = 4G-6 (covers 5-wide OR for 12 score cols)
  const int p2 = 4 * G - 6;
  const int pw2 = (p2 < 0) ? 0 : (p2 >> 5);
  const int psh2 = (p2 < 0) ? 0 : (p2 & 31);
  const int pls2 = (p2 < 0) ? -p2 : 0;

  float4 hw[5], cw[5];
  uint32_t snr[5], mor[5], cnb[5];
  constexpr int NK = (PASS == 0) ? 12 : 16;
#pragma unroll
  for (int k = 0; k < NK; ++k) {
    if (PASS != 0) {
      const int mr = r0 - 4 + k;
      uint32_t morrow = 0, cnib = 0;
      if ((unsigned)mr < (unsigned)RROWS) {
        const uint32_t* srow = MIN_ + mr * MW;
        uint64_t X = (uint64_t)srow[pw2] | ((uint64_t)srow[pw2 + 1] << 32);
        uint64_t win = pls2 ? (X << pls2) : (X >> psh2);
        uint64_t t5 = win | (win >> 1) | (win >> 2) | (win >> 3) | (win >> 4);
        morrow = (uint32_t)t5 & 0xFFFu;
        cnib = (uint32_t)(win >> 6) & 0xFu;
      }
      mor[k % 5] = morrow;
      cnb[k % 5] = cnib;
    }
    const int ks = (PASS == 0) ? k : k - 4;
    if (ks >= 0) {
      const int sr = r0 - 2 + ks;
      uint32_t supp = 0;
      if (PASS != 0) supp = mor[0] | mor[1] | mor[2] | mor[3] | mor[4];
      const float* rowp = S + sr * STR + 4 * G;
      float4 d = ld4(rowp);
      float4 a = (G > 0) ? ld4(rowp - 4) : d;  // garbage-only cols, safe
      float4 e = (G < NG - 1) ? ld4(rowp + 4) : d;
      if (PASS != 0) {
        if (supp & 0x001u) a.x = 0.f;
        if (supp & 0x002u) a.y = 0.f;
        if (supp & 0x004u) a.z = 0.f;
        if (supp & 0x008u) a.w = 0.f;
        if (supp & 0x010u) d.x = 0.f;
        if (supp & 0x020u) d.y = 0.f;
        if (supp & 0x040u) d.z = 0.f;
        if (supp & 0x080u) d.w = 0.f;
        if (supp & 0x100u) e.x = 0.f;
        if (supp & 0x200u) e.y = 0.f;
        if (supp & 0x400u) e.z = 0.f;
        if (supp & 0x800u) e.w = 0.f;
      }
      float4 hm;
      hm.x = max5(a.z, a.w, d.x, d.y, d.z);
      hm.y = max5(a.w, d.x, d.y, d.z, d.w);
      hm.z = max5(d.x, d.y, d.z, d.w, e.x);
      hm.w = max5(d.y, d.z, d.w, e.x, e.y);
      hw[ks % 5] = hm;
      cw[ks % 5] = d;
      snr[ks % 5] = (supp >> 4) & 0xFu;
      if (ks >= 4) {
        const int rq = r0 - 4 + ks;  // output row: r0..r0+7
        const int gy = y0 - 8 + rq;
        float4 vm;
        vm.x = max5(hw[0].x, hw[1].x, hw[2].x, hw[3].x, hw[4].x);
        vm.y = max5(hw[0].y, hw[1].y, hw[2].y, hw[3].y, hw[4].y);
        vm.z = max5(hw[0].z, hw[1].z, hw[2].z, hw[3].z, hw[4].z);
        vm.w = max5(hw[0].w, hw[1].w, hw[2].w, hw[3].w, hw[4].w);
        float4 c = cw[(ks + 3) % 5];  // center (masked for PASS 1/2)
        uint32_t nm = (uint32_t)(c.x == vm.x) | ((uint32_t)(c.y == vm.y) << 1) |
                      ((uint32_t)(c.z == vm.z) << 2) | ((uint32_t)(c.w == vm.w) << 3);
        nm &= ((unsigned)gy < (unsigned)H) ? colm : 0u;
        const int widx = rq * MW + (G >> 3);
        const int shift = 4 * (G & 7);
        if (PASS == 0) {
          if (nm) atomicOr(&MOUT[widx], nm << shift);
        } else if (PASS == 1) {
          uint32_t fin = cnb[ks % 5] | (nm & ~snr[(ks + 3) % 5]);
          if (fin) atomicOr(&MOUT[widx], fin << shift);
        } else {
          uint32_t fin = cnb[ks % 5] | (nm & ~snr[(ks + 3) % 5]);
          if (fin && G >= 2 && G < 18 && gy >= 2 && gy < H - 2) {
#pragma unroll
            for (int j = 0; j < 4; ++j) {
              if ((fin >> j) & 1u) {
                int gx = gx0 + j;
                if (gx >= 2 && gx < W - 2) {
                  float sval = S[rq * STR + 4 * G + j];  // original (unmasked) score
                  if (sval > 0.0f) {
                    uint32_t bits = __float_as_uint(sval);
                    uint32_t flat = (uint32_t)(gy * W + gx);
                    uint64_t key = ((uint64_t)bits << 32) | (uint64_t)(0xFFFFFFFFu - flat);
                    uint32_t pos = atomicAdd(cnt_loc, 1u);
                    if (pos < (uint32_t)LIST_CAP) {
                      list[pos] = key;
                    } else {  // tie overflow: direct global append + exp hist (rare)
                      uint32_t pp = atomicAdd(&cand_count[b], 1u);
                      if (pp < (uint32_t)CAND_CAP) cand[(size_t)b * CAND_CAP + pp] = key;
                      atomicAdd(&gehist[(size_t)b * 256 + (bits >> 23)], 1u);
                    }
                  }
                }
              }
            }
          }
        }
      }
    }
  }
}

// ---------------- fused 3-pass NMS + candidate emit + exp-hist tail ------------------
__global__ void __launch_bounds__(256, 5) k_nms(const float* __restrict__ scores,
                                                uint64_t* __restrict__ cand,
                                                uint32_t* __restrict__ cand_count,
                                                uint32_t* __restrict__ gehist) {
  __shared__ float S[RROWS * STR];
  __shared__ uint32_t M0s[RROWS * MW];
  __shared__ uint32_t M1s[RROWS * MW];
  __shared__ uint64_t list[LIST_CAP];
  __shared__ uint32_t cnt_loc, base_g;
  const int b = blockIdx.z;
  const int x0 = blockIdx.x * 64, y0 = blockIdx.y * 64;
  const int tid = threadIdx.x;
  const float* img = scores + (size_t)b * H * W;
  if (tid == 0) cnt_loc = 0;

  for (int u = tid; u < RROWS * NG; u += 256) {
    int r = u / NG, G = u % NG;
    int gy = y0 - 8 + r, gx = x0 - 8 + 4 * G;
    float4 v;
    if ((unsigned)gy < (unsigned)H && (unsigned)gx < (unsigned)W)
      v = ld4(img + (size_t)gy * W + gx);
    else
      v = make_float4(-INFINITY, -INFINITY, -INFINITY, -INFINITY);
    *reinterpret_cast<float4*>(&S[r * STR + 4 * G]) = v;
  }
  for (int i = tid; i < RROWS * MW; i += 256) {
    M0s[i] = 0;
    M1s[i] = 0;
  }
  __syncthreads();
  if (tid < NUNIT_M)
    score_pass<0>(tid, x0, y0, S, nullptr, M0s, nullptr, nullptr, nullptr, nullptr,
                  nullptr, b);
  __syncthreads();
  if (tid < NUNIT_M)
    score_pass<1>(tid, x0, y0, S, M0s, M1s, nullptr, nullptr, nullptr, nullptr,
                  nullptr, b);
  __syncthreads();
  if (tid < NUNIT_E)
    score_pass<2>(tid, x0, y0, S, M1s, nullptr, list, &cnt_loc, cand, cand_count,
                  gehist, b);
  __syncthreads();
  uint32_t nblk = cnt_loc;
  uint32_t nmain = nblk < (uint32_t)LIST_CAP ? nblk : (uint32_t)LIST_CAP;
  if (tid == 0) base_g = atomicAdd(&cand_count[b], nmain);
  M0s[tid] = 0;  // reuse M0s (dead after pass 1) as 256-bin exp hist
  __syncthreads();
  uint32_t bg = base_g;
  for (uint32_t i = tid; i < nmain; i += 256) {
    uint64_t key = list[i];
    uint32_t pp = bg + i;
    if (pp < (uint32_t)CAND_CAP) cand[(size_t)b * CAND_CAP + pp] = key;
    atomicAdd(&M0s[(uint32_t)(key >> 55)], 1u);  // exp bucket = score_bits>>23 (<=126)
  }
  __syncthreads();
  uint32_t v = M0s[tid];
  if (v) atomicAdd(&gehist[(size_t)b * 256 + tid], v);  // ~4-6 sparse bins per block
}

// ---------------- fine histogram within crossing exponent E --------------------------
__global__ void __launch_bounds__(256) k_fhist(const uint64_t* __restrict__ cand,
                                               const uint32_t* __restrict__ cand_count,
                                               const uint32_t* __restrict__ gehist,
                                               uint32_t* __restrict__ gfhist) {
  __shared__ uint32_t fh[256];
  __shared__ uint32_t ehl[256];
  __shared__ int sE;
  const int b = blockIdx.y, t = threadIdx.x;
  uint32_t n = cand_count[b];
  if (n > (uint32_t)CAND_CAP) n = CAND_CAP;
  fh[t] = 0;
  ehl[t] = gehist[b * 256 + t];
  __syncthreads();
  if (t == 0) {
    uint32_t run = 0;
    int E = -1;
    for (int e = 255; e >= 0; --e) {
      uint32_t nrun = run + ehl[e];
      if (run < (uint32_t)TOPK && nrun >= (uint32_t)TOPK) E = e;
      run = nrun;
    }
    if (run < (uint32_t)TOPK) E = -1;  // fewer than TOPK candidates: select all
    sE = E;
  }
  __syncthreads();
  const int E = sE;
  if (E < 0) return;
  const uint64_t* cb = cand + (size_t)b * CAND_CAP;
  for (uint32_t i = blockIdx.x * 256 + t; i < n; i += NHB * 256) {
    uint64_t key = cb[i];
    if ((uint32_t)(key >> 55) == (uint32_t)E)
      atomicAdd(&fh[(uint32_t)(key >> 47) & 0xFFu], 1u);
  }
  __syncthreads();
  uint32_t v = fh[t];
  if (v) atomicAdd(&gfhist[b * 256 + t], v);
}

// ---------------- compact (threshold-find fused in) ----------------------------------
__global__ void __launch_bounds__(1024) k_compact(const uint64_t* __restrict__ cand,
                                                  const uint32_t* __restrict__ cand_count,
                                                  const uint32_t* __restrict__ gehist,
                                                  const uint32_t* __restrict__ gfhist,
                                                  uint64_t* __restrict__ sel,
                                                  uint32_t* __restrict__ sel_count,
                                                  uint32_t* __restrict__ rankg) {
  __shared__ uint64_t list[1024];
  __shared__ uint32_t cnt_loc, base_g;
  __shared__ uint32_t eh[256], fh[256];
  __shared__ int sE;
  __shared__ uint32_t sAbove;
  __shared__ uint64_t s_thr;
  const int b = blockIdx.y;
  uint32_t n = cand_count[b];
  if (n > (uint32_t)CAND_CAP) n = CAND_CAP;
  const int tid = threadIdx.x;
  if (tid == 0) {
    cnt_loc = 0;
    sE = -1;
    s_thr = 0ull;
  }
  if (tid < 256) {
    eh[tid] = gehist[b * 256 + tid];
    fh[tid] = gfhist[b * 256 + tid];
  }
  __syncthreads();
  for (int d = 1; d < 256; d <<= 1) {
    uint32_t ve = 0, vf = 0;
    if (tid < 256) {
      ve = (tid + d < 256) ? eh[tid + d] : 0u;
      vf = (tid + d < 256) ? fh[tid + d] : 0u;
    }
    __syncthreads();
    if (tid < 256) {
      eh[tid] += ve;
      fh[tid] += vf;
    }
    __syncthreads();
  }
  if (tid < 256) {
    uint32_t nxt = (tid < 255) ? eh[tid + 1] : 0u;
    if (eh[tid] >= (uint32_t)TOPK && nxt < (uint32_t)TOPK) {
      sE = tid;
      sAbove = nxt;  // count of keys with exponent > E (< TOPK by construction)
    }
  }
  __syncthreads();
  if (sE >= 0 && tid < 256) {
    uint32_t above = sAbove;
    uint32_t Fn = (tid < 255) ? fh[tid + 1] : 0u;
    if (above + fh[tid] >= (uint32_t)TOPK && above + Fn < (uint32_t)TOPK)
      s_thr = ((uint64_t)(((uint32_t)sE << 8) | (uint32_t)tid)) << 47;
  }
  __syncthreads();
  const uint64_t thr = s_thr;  // 0 => select all (fewer than TOPK candidates)
  uint32_t i = blockIdx.x * 1024 + tid;
  if (i < n) {
    uint64_t key = cand[(size_t)b * CAND_CAP + i];
    if (key >= thr) {
      uint32_t pos = atomicAdd(&cnt_loc, 1u);
      list[pos] = key;
    }
  }
  __syncthreads();
  uint32_t nblk = cnt_loc;
  if (tid == 0 && nblk > 0) base_g = atomicAdd(&sel_count[b], nblk);
  __syncthreads();
  if (nblk > 0 && (uint32_t)tid < nblk) {
    uint32_t pp = base_g + tid;
    if (pp < (uint32_t)SEL_CAP) {
      sel[(size_t)b * SEL_CAP + pp] = list[tid];
      rankg[(size_t)b * SEL_CAP + pp] = 0u;
    }
  }
}

// ---------------- tiled partial ranking ----------------------------------------------
__global__ void __launch_bounds__(RK_ME) k_rank_part(const uint64_t* __restrict__ sel,
                                                     const uint32_t* __restrict__ sel_count,
                                                     uint32_t* __restrict__ rankg) {
  __shared__ uint64_t keys[RK_CH];  // 8 KiB
  const int b = blockIdx.z;
  uint32_t n = sel_count[b];
  if (n > (uint32_t)SEL_CAP) n = SEL_CAP;
  const uint32_t me0 = blockIdx.x * RK_ME;
  const uint32_t c0 = blockIdx.y * RK_CH;
  if (me0 >= n || c0 >= n) return;
  const uint64_t* sb = sel + (size_t)b * SEL_CAP;
  uint32_t clen = n - c0;
  if (clen > (uint32_t)RK_CH) clen = RK_CH;
  for (uint32_t i = threadIdx.x; i < clen; i += RK_ME) keys[i] = sb[c0 + i];
  __syncthreads();
  const uint32_t me = me0 + threadIdx.x;
  if (me >= n) return;
  const uint64_t kme = sb[me];
  uint32_t rank = 0;
  uint32_t i = 0;
  for (; i + 8 <= clen; i += 8) {
    rank += (keys[i] > kme);
    rank += (keys[i + 1] > kme);
    rank += (keys[i + 2] > kme);
    rank += (keys[i + 3] > kme);
    rank += (keys[i + 4] > kme);
    rank += (keys[i + 5] > kme);
    rank += (keys[i + 6] > kme);
    rank += (keys[i + 7] > kme);
  }
  for (; i < clen; ++i) rank += (keys[i] > kme);
  if (rank) atomicAdd(&rankg[(size_t)b * SEL_CAP + me], rank);
}

// ---------------- refinement (scatter fused in): 8 lanes per sel item ----------------
__global__ void __launch_bounds__(256) k_refine(const float* __restrict__ scores,
                                                const uint64_t* __restrict__ sel,
                                                const uint32_t* __restrict__ sel_count,
                                                const uint32_t* __restrict__ rankg,
                                                float* __restrict__ out) {
  int gid = blockIdx.x * 256 + threadIdx.x;
  int idx = gid >> 3, ln = gid & 7;
  const int b = idx / SEL_CAP;
  const int i = idx % SEL_CAP;
  uint32_t n = sel_count[b];
  if (n > (uint32_t)SEL_CAP) n = SEL_CAP;
  if ((uint32_t)i >= n) return;  // uniform across the 8-lane group
  uint32_t r = rankg[(size_t)b * SEL_CAP + i];
  if (r >= (uint32_t)TOPK) return;  // uniform across the group
  uint64_t key = sel[(size_t)b * SEL_CAP + i];
  uint32_t flat = 0xFFFFFFFFu - (uint32_t)(key & 0xFFFFFFFFull);
  if (flat >= (uint32_t)(H * W)) flat = 0;  // safety guard
  const int ix = (int)(flat % W);
  const int iy = (int)(flat / W);
  const float* img = scores + (size_t)b * H * W;

  const int nt = (ln == 0) ? 4 : 3;
  float v[4];
  float mymax = -INFINITY;
#pragma unroll
  for (int q = 0; q < 4; ++q) {
    if (q < nt) {
      int t = ln + 8 * q;
      int y = iy + t / 5 - 2, x = ix + t % 5 - 2;
      float val = ((unsigned)x < (unsigned)W && (unsigned)y < (unsigned)H)
                      ? img[(size_t)y * W + x] : 0.0f;
      v[q] = val;
      mymax = fmaxf(mymax, val);
    }
  }
#pragma unroll
  for (int m = 1; m < 8; m <<= 1) mymax = fmaxf(mymax, __shfl_xor(mymax, m));
  float e[4];
  float sum = 0.f, sx = 0.f, sy = 0.f;
#pragma unroll
  for (int q = 0; q < 4; ++q) {
    if (q < nt) {
      int t = ln + 8 * q;
      float ev = expf((v[q] - mymax) / 0.1f);
      e[q] = ev;
      sum += ev;
      sx += ev * (float)(t % 5 - 2);
      sy += ev * (float)(t / 5 - 2);
    }
  }
#pragma unroll
  for (int m = 1; m < 8; m <<= 1) {
    sum += __shfl_xor(sum, m);
    sx += __shfl_xor(sx, m);
    sy += __shfl_xor(sy, m);
  }
  float rx = sx / sum, ry = sy / sum;
  float dsp = 0.f;
#pragma unroll
  for (int q = 0; q < 4; ++q) {
    if (q < nt) {
      int t = ln + 8 * q;
      float dx = ((float)(t % 5 - 2) - rx) * 0.5f;
      float dy = ((float)(t / 5 - 2) - ry) * 0.5f;
      dsp += e[q] * (dx * dx + dy * dy);
    }
  }
#pragma unroll
  for (int m = 1; m < 8; m <<= 1) dsp += __shfl_xor(dsp, m);
  if (ln != 0) return;
  dsp /= sum;
  float kx = ((float)ix + rx) / 1023.0f * 2.0f - 1.0f;
  float ky = ((float)iy + ry) / 1023.0f * 2.0f - 1.0f;
  float px = (kx + 1.0f) * 0.5f * 1023.0f;
  float py = (ky + 1.0f) * 0.5f * 1023.0f;
  float x0f = floorf(px), y0f = floorf(py);
  float wx1 = px - x0f, wx0 = 1.0f - wx1;
  float wy1 = py - y0f, wy0 = 1.0f - wy1;
  int x0 = (int)x0f, y0 = (int)y0f;
  float sc = 0.0f;
  {
    int xs[2] = {x0, x0 + 1};
    int ys[2] = {y0, y0 + 1};
    float wxs[2] = {wx0, wx1};
    float wys[2] = {wy0, wy1};
#pragma unroll
    for (int yy = 0; yy < 2; ++yy)
#pragma unroll
      for (int xx = 0; xx < 2; ++xx) {
        int xi = xs[xx], yi = ys[yy];
        bool valid = (xi >= 0 && xi < W && yi >= 0 && yi < H);
        int xc = min(max(xi, 0), W - 1);
        int yc = min(max(yi, 0), H - 1);
        float vv = valid ? img[(size_t)yc * W + xc] : 0.0f;
        sc += vv * (wxs[xx] * wys[yy]);
      }
  }
  out[((size_t)b * TOPK + r) * 2 + 0] = kx;
  out[((size_t)b * TOPK + r) * 2 + 1] = ky;
  out[(size_t)B * TOPK * 2 + (size_t)b * TOPK + r] = sc;
  out[(size_t)B * TOPK * 3 + (size_t)b * TOPK + r] = dsp;
}

}  // namespace

extern "C" void kernel_launch(void* const* d_in, const int* in_sizes, int n_in,
                              void* d_out, int out_size, void* d_ws, size_t ws_size,
                              hipStream_t stream) {
  const float* scores = (const float*)d_in[0];
  float* out = (float*)d_out;
  char* ws = (char*)d_ws;

  uint32_t* cnt = (uint32_t*)(ws + OFF_CNT);
  uint32_t* cand_count = cnt;                    // [B]
  uint32_t* sel_count  = cnt + 8;                // [B]
  uint32_t* gehist = (uint32_t*)(ws + OFF_EH);   // [B][256]
  uint32_t* gfhist = (uint32_t*)(ws + OFF_FH);   // [B][256]
  uint32_t* rankg = (uint32_t*)(ws + OFF_RANK);  // [B][SEL_CAP]
  uint64_t* sel  = (uint64_t*)(ws + OFF_SEL);
  uint64_t* cand = (uint64_t*)(ws + OFF_CAND);

  hipMemsetAsync(ws + OFF_CNT, 0, MEMSET_BYTES, stream);

  k_nms<<<dim3(W / 64, H / 64, B), 256, 0, stream>>>(scores, cand, cand_count, gehist);
  k_fhist<<<dim3(NHB, B), 256, 0, stream>>>(cand, cand_count, gehist, gfhist);
  k_compact<<<dim3(CAND_CAP / 1024, B), 1024, 0, stream>>>(cand, cand_count, gehist,
                                                           gfhist, sel, sel_count, rankg);
  k_rank_part<<<dim3(SEL_CAP / RK_ME, SEL_CAP / RK_CH, B), RK_ME, 0, stream>>>(
      sel, sel_count, rankg);
  k_refine<<<(B * SEL_CAP * 8) / 256, 256, 0, stream>>>(scores, sel, sel_count, rankg,
                                                        out);
}

// Round 13
// 195.485 us; speedup vs baseline: 5.8824x; 1.0020x over previous
//
#include <hip/hip_runtime.h>
#include <stdint.h>

namespace {

constexpr int B = 8;
constexpr int H = 1024;
constexpr int W = 1024;
constexpr int TOPK = 4096;
constexpr int CAND_CAP = 131072;  // per batch
constexpr int SEL_CAP = 16384;    // per batch
constexpr int LIST_CAP = 320;     // per 64x64 tile
constexpr int NHB = 32;           // fhist slice blocks per batch

// fused-NMS tile: 64x64 interior, radius-8 staged halo (round-12: halo-12 was
// over-provisioned — chain needs only 6, rounded to 8 for float4 alignment).
// Validity chain: M0 computed rows [4,75] (valid: scores rows 2..77 staged);
// M1 computed rows [4,75] (needs M0 rows 2..77; rows <4/>75 read zeros, and those
// M1 rows are never consumed); emission rows [8,71] = gy in [y0, y0+63], consuming
// M1 rows 6..73 (computed+valid) and scores rows 6..73. Cols symmetric.
constexpr int RROWS = 78;   // staged score rows (gy = y0-8+r)
constexpr int NG = 20;      // float4 col-groups (80 cols, gx0 = x0-8+4G)
constexpr int STR = 80;     // score row stride (floats)
constexpr int MW = 5;       // mask words/row (3 used + 2 zero pad; stride-5 debanks)
constexpr int NSM = 9;      // mask-pass strips: r0 = 4+8s -> rows 4..75
constexpr int NSE = 8;      // emission strips:  r0 = 8+8s -> rows 8..71
constexpr int NUNIT_M = NG * NSM;  // 180
constexpr int NUNIT_E = NG * NSE;  // 160
// LDS ~30.7 KiB -> hardware fits 5 blocks/CU by LDS alone.
// Round-13 lesson: __launch_bounds__(256,5) squeezed VGPR 52->44 and SPILLED the
// hw[5]/cw[5] ring state to scratch (VALUBusy 59->27%, k_nms 64->106us). Keep the
// allocator at min-4 (VGPR 52, no spills); occupancy still reaches 5 via LDS.

// rank kernel tiling (round-5 lesson: 2D (me,chunk) split keeps ~680 blocks active)
constexpr int RK_ME = 256;   // me-keys per block (1/thread)
constexpr int RK_CH = 1024;  // chunk keys staged in LDS per block

// workspace layout (bytes).
// Round-9 lesson: cooperative grid.sync on 8-XCD MI355X costs ~200us/sync —
// kernel boundaries are CHEAPER than grid syncs; stay multi-kernel.
constexpr size_t OFF_CNT   = 0;                                   // 4 KiB
constexpr size_t OFF_EH    = 4096;                                // B*256*4 = 8 KiB
constexpr size_t OFF_FH    = OFF_EH + (size_t)B * 256 * 4;        // 8 KiB
constexpr size_t OFF_RANK  = OFF_FH + (size_t)B * 256 * 4;        // B*SEL_CAP*4 = 512 KiB
constexpr size_t OFF_SEL   = OFF_RANK + (size_t)B * SEL_CAP * 4;  // 1 MiB
constexpr size_t OFF_CAND  = OFF_SEL + (size_t)B * SEL_CAP * 8;   // 8 MiB
constexpr size_t MEMSET_BYTES = OFF_RANK;  // cnt + hist pages only (20.5 KiB)

__device__ __forceinline__ float max5(float a, float b, float c, float d, float e) {
  return fmaxf(fmaxf(fmaxf(a, b), fmaxf(c, d)), e);
}
__device__ __forceinline__ float4 ld4(const float* p) {
  return *reinterpret_cast<const float4*>(p);
}

// One unit: col-group G in [0,NG), strip s -> output rows r0..r0+7, where
// r0 = 4+8s for mask passes (0/1) and 8+8s for emission (2). PASS 0: plain
// local-max -> M0. PASS 1/2: inline dilation of the previous mask via a
// 2-row-lookahead ring. PASS 1 writes cumulative M1 = M0|new. PASS 2 emits
// candidates into the LDS list (overflow keys append+hist globally — rare).
template <int PASS>
__device__ __forceinline__ void score_pass(
    int u, int x0, int y0, const float* __restrict__ S,
    const uint32_t* __restrict__ MIN_, uint32_t* __restrict__ MOUT,
    uint64_t* list, uint32_t* cnt_loc, uint64_t* cand, uint32_t* cand_count,
    uint32_t* __restrict__ gehist, int b) {
  const int G = u % NG, s = u / NG;
  const int r0 = ((PASS == 2) ? 8 : 4) + 8 * s;
  const int gx0 = x0 - 8 + 4 * G;
  uint32_t colm = 0;
#pragma unroll
  for (int j = 0; j < 4; ++j)
    if ((unsigned)(gx0 + j) < (unsigned)W) colm |= 1u << j;

  // 16-col mask window starting at p2 = 4G-6 (covers 5-wide OR for 12 score cols)
  const int p2 = 4 * G - 6;
  const int pw2 = (p2 < 0) ? 0 : (p2 >> 5);
  const int psh2 = (p2 < 0) ? 0 : (p2 & 31);
  const int pls2 = (p2 < 0) ? -p2 : 0;

  float4 hw[5], cw[5];
  uint32_t snr[5], mor[5], cnb[5];
  constexpr int NK = (PASS == 0) ? 12 : 16;
#pragma unroll
  for (int k = 0; k < NK; ++k) {
    if (PASS != 0) {
      const int mr = r0 - 4 + k;
      uint32_t morrow = 0, cnib = 0;
      if ((unsigned)mr < (unsigned)RROWS) {
        const uint32_t* srow = MIN_ + mr * MW;
        uint64_t X = (uint64_t)srow[pw2] | ((uint64_t)srow[pw2 + 1] << 32);
        uint64_t win = pls2 ? (X << pls2) : (X >> psh2);
        uint64_t t5 = win | (win >> 1) | (win >> 2) | (win >> 3) | (win >> 4);
        morrow = (uint32_t)t5 & 0xFFFu;
        cnib = (uint32_t)(win >> 6) & 0xFu;
      }
      mor[k % 5] = morrow;
      cnb[k % 5] = cnib;
    }
    const int ks = (PASS == 0) ? k : k - 4;
    if (ks >= 0) {
      const int sr = r0 - 2 + ks;
      uint32_t supp = 0;
      if (PASS != 0) supp = mor[0] | mor[1] | mor[2] | mor[3] | mor[4];
      const float* rowp = S + sr * STR + 4 * G;
      float4 d = ld4(rowp);
      float4 a = (G > 0) ? ld4(rowp - 4) : d;  // garbage-only cols, safe
      float4 e = (G < NG - 1) ? ld4(rowp + 4) : d;
      if (PASS != 0) {
        if (supp & 0x001u) a.x = 0.f;
        if (supp & 0x002u) a.y = 0.f;
        if (supp & 0x004u) a.z = 0.f;
        if (supp & 0x008u) a.w = 0.f;
        if (supp & 0x010u) d.x = 0.f;
        if (supp & 0x020u) d.y = 0.f;
        if (supp & 0x040u) d.z = 0.f;
        if (supp & 0x080u) d.w = 0.f;
        if (supp & 0x100u) e.x = 0.f;
        if (supp & 0x200u) e.y = 0.f;
        if (supp & 0x400u) e.z = 0.f;
        if (supp & 0x800u) e.w = 0.f;
      }
      float4 hm;
      hm.x = max5(a.z, a.w, d.x, d.y, d.z);
      hm.y = max5(a.w, d.x, d.y, d.z, d.w);
      hm.z = max5(d.x, d.y, d.z, d.w, e.x);
      hm.w = max5(d.y, d.z, d.w, e.x, e.y);
      hw[ks % 5] = hm;
      cw[ks % 5] = d;
      snr[ks % 5] = (supp >> 4) & 0xFu;
      if (ks >= 4) {
        const int rq = r0 - 4 + ks;  // output row: r0..r0+7
        const int gy = y0 - 8 + rq;
        float4 vm;
        vm.x = max5(hw[0].x, hw[1].x, hw[2].x, hw[3].x, hw[4].x);
        vm.y = max5(hw[0].y, hw[1].y, hw[2].y, hw[3].y, hw[4].y);
        vm.z = max5(hw[0].z, hw[1].z, hw[2].z, hw[3].z, hw[4].z);
        vm.w = max5(hw[0].w, hw[1].w, hw[2].w, hw[3].w, hw[4].w);
        float4 c = cw[(ks + 3) % 5];  // center (masked for PASS 1/2)
        uint32_t nm = (uint32_t)(c.x == vm.x) | ((uint32_t)(c.y == vm.y) << 1) |
                      ((uint32_t)(c.z == vm.z) << 2) | ((uint32_t)(c.w == vm.w) << 3);
        nm &= ((unsigned)gy < (unsigned)H) ? colm : 0u;
        const int widx = rq * MW + (G >> 3);
        const int shift = 4 * (G & 7);
        if (PASS == 0) {
          if (nm) atomicOr(&MOUT[widx], nm << shift);
        } else if (PASS == 1) {
          uint32_t fin = cnb[ks % 5] | (nm & ~snr[(ks + 3) % 5]);
          if (fin) atomicOr(&MOUT[widx], fin << shift);
        } else {
          uint32_t fin = cnb[ks % 5] | (nm & ~snr[(ks + 3) % 5]);
          if (fin && G >= 2 && G < 18 && gy >= 2 && gy < H - 2) {
#pragma unroll
            for (int j = 0; j < 4; ++j) {
              if ((fin >> j) & 1u) {
                int gx = gx0 + j;
                if (gx >= 2 && gx < W - 2) {
                  float sval = S[rq * STR + 4 * G + j];  // original (unmasked) score
                  if (sval > 0.0f) {
                    uint32_t bits = __float_as_uint(sval);
                    uint32_t flat = (uint32_t)(gy * W + gx);
                    uint64_t key = ((uint64_t)bits << 32) | (uint64_t)(0xFFFFFFFFu - flat);
                    uint32_t pos = atomicAdd(cnt_loc, 1u);
                    if (pos < (uint32_t)LIST_CAP) {
                      list[pos] = key;
                    } else {  // tie overflow: direct global append + exp hist (rare)
                      uint32_t pp = atomicAdd(&cand_count[b], 1u);
                      if (pp < (uint32_t)CAND_CAP) cand[(size_t)b * CAND_CAP + pp] = key;
                      atomicAdd(&gehist[(size_t)b * 256 + (bits >> 23)], 1u);
                    }
                  }
                }
              }
            }
          }
        }
      }
    }
  }
}

// ---------------- fused 3-pass NMS + candidate emit + exp-hist tail ------------------
__global__ void __launch_bounds__(256, 4) k_nms(const float* __restrict__ scores,
                                                uint64_t* __restrict__ cand,
                                                uint32_t* __restrict__ cand_count,
                                                uint32_t* __restrict__ gehist) {
  __shared__ float S[RROWS * STR];
  __shared__ uint32_t M0s[RROWS * MW];
  __shared__ uint32_t M1s[RROWS * MW];
  __shared__ uint64_t list[LIST_CAP];
  __shared__ uint32_t cnt_loc, base_g;
  const int b = blockIdx.z;
  const int x0 = blockIdx.x * 64, y0 = blockIdx.y * 64;
  const int tid = threadIdx.x;
  const float* img = scores + (size_t)b * H * W;
  if (tid == 0) cnt_loc = 0;

  for (int u = tid; u < RROWS * NG; u += 256) {
    int r = u / NG, G = u % NG;
    int gy = y0 - 8 + r, gx = x0 - 8 + 4 * G;
    float4 v;
    if ((unsigned)gy < (unsigned)H && (unsigned)gx < (unsigned)W)
      v = ld4(img + (size_t)gy * W + gx);
    else
      v = make_float4(-INFINITY, -INFINITY, -INFINITY, -INFINITY);
    *reinterpret_cast<float4*>(&S[r * STR + 4 * G]) = v;
  }
  for (int i = tid; i < RROWS * MW; i += 256) {
    M0s[i] = 0;
    M1s[i] = 0;
  }
  __syncthreads();
  if (tid < NUNIT_M)
    score_pass<0>(tid, x0, y0, S, nullptr, M0s, nullptr, nullptr, nullptr, nullptr,
                  nullptr, b);
  __syncthreads();
  if (tid < NUNIT_M)
    score_pass<1>(tid, x0, y0, S, M0s, M1s, nullptr, nullptr, nullptr, nullptr,
                  nullptr, b);
  __syncthreads();
  if (tid < NUNIT_E)
    score_pass<2>(tid, x0, y0, S, M1s, nullptr, list, &cnt_loc, cand, cand_count,
                  gehist, b);
  __syncthreads();
  uint32_t nblk = cnt_loc;
  uint32_t nmain = nblk < (uint32_t)LIST_CAP ? nblk : (uint32_t)LIST_CAP;
  if (tid == 0) base_g = atomicAdd(&cand_count[b], nmain);
  M0s[tid] = 0;  // reuse M0s (dead after pass 1) as 256-bin exp hist
  __syncthreads();
  uint32_t bg = base_g;
  for (uint32_t i = tid; i < nmain; i += 256) {
    uint64_t key = list[i];
    uint32_t pp = bg + i;
    if (pp < (uint32_t)CAND_CAP) cand[(size_t)b * CAND_CAP + pp] = key;
    atomicAdd(&M0s[(uint32_t)(key >> 55)], 1u);  // exp bucket = score_bits>>23 (<=126)
  }
  __syncthreads();
  uint32_t v = M0s[tid];
  if (v) atomicAdd(&gehist[(size_t)b * 256 + tid], v);  // ~4-6 sparse bins per block
}

// ---------------- fine histogram within crossing exponent E --------------------------
__global__ void __launch_bounds__(256) k_fhist(const uint64_t* __restrict__ cand,
                                               const uint32_t* __restrict__ cand_count,
                                               const uint32_t* __restrict__ gehist,
                                               uint32_t* __restrict__ gfhist) {
  __shared__ uint32_t fh[256];
  __shared__ uint32_t ehl[256];
  __shared__ int sE;
  const int b = blockIdx.y, t = threadIdx.x;
  uint32_t n = cand_count[b];
  if (n > (uint32_t)CAND_CAP) n = CAND_CAP;
  fh[t] = 0;
  ehl[t] = gehist[b * 256 + t];
  __syncthreads();
  if (t == 0) {
    uint32_t run = 0;
    int E = -1;
    for (int e = 255; e >= 0; --e) {
      uint32_t nrun = run + ehl[e];
      if (run < (uint32_t)TOPK && nrun >= (uint32_t)TOPK) E = e;
      run = nrun;
    }
    if (run < (uint32_t)TOPK) E = -1;  // fewer than TOPK candidates: select all
    sE = E;
  }
  __syncthreads();
  const int E = sE;
  if (E < 0) return;
  const uint64_t* cb = cand + (size_t)b * CAND_CAP;
  for (uint32_t i = blockIdx.x * 256 + t; i < n; i += NHB * 256) {
    uint64_t key = cb[i];
    if ((uint32_t)(key >> 55) == (uint32_t)E)
      atomicAdd(&fh[(uint32_t)(key >> 47) & 0xFFu], 1u);
  }
  __syncthreads();
  uint32_t v = fh[t];
  if (v) atomicAdd(&gfhist[b * 256 + t], v);
}

// ---------------- compact (threshold-find fused in) ----------------------------------
__global__ void __launch_bounds__(1024) k_compact(const uint64_t* __restrict__ cand,
                                                  const uint32_t* __restrict__ cand_count,
                                                  const uint32_t* __restrict__ gehist,
                                                  const uint32_t* __restrict__ gfhist,
                                                  uint64_t* __restrict__ sel,
                                                  uint32_t* __restrict__ sel_count,
                                                  uint32_t* __restrict__ rankg) {
  __shared__ uint64_t list[1024];
  __shared__ uint32_t cnt_loc, base_g;
  __shared__ uint32_t eh[256], fh[256];
  __shared__ int sE;
  __shared__ uint32_t sAbove;
  __shared__ uint64_t s_thr;
  const int b = blockIdx.y;
  uint32_t n = cand_count[b];
  if (n > (uint32_t)CAND_CAP) n = CAND_CAP;
  const int tid = threadIdx.x;
  if (tid == 0) {
    cnt_loc = 0;
    sE = -1;
    s_thr = 0ull;
  }
  if (tid < 256) {
    eh[tid] = gehist[b * 256 + tid];
    fh[tid] = gfhist[b * 256 + tid];
  }
  __syncthreads();
  for (int d = 1; d < 256; d <<= 1) {
    uint32_t ve = 0, vf = 0;
    if (tid < 256) {
      ve = (tid + d < 256) ? eh[tid + d] : 0u;
      vf = (tid + d < 256) ? fh[tid + d] : 0u;
    }
    __syncthreads();
    if (tid < 256) {
      eh[tid] += ve;
      fh[tid] += vf;
    }
    __syncthreads();
  }
  if (tid < 256) {
    uint32_t nxt = (tid < 255) ? eh[tid + 1] : 0u;
    if (eh[tid] >= (uint32_t)TOPK && nxt < (uint32_t)TOPK) {
      sE = tid;
      sAbove = nxt;  // count of keys with exponent > E (< TOPK by construction)
    }
  }
  __syncthreads();
  if (sE >= 0 && tid < 256) {
    uint32_t above = sAbove;
    uint32_t Fn = (tid < 255) ? fh[tid + 1] : 0u;
    if (above + fh[tid] >= (uint32_t)TOPK && above + Fn < (uint32_t)TOPK)
      s_thr = ((uint64_t)(((uint32_t)sE << 8) | (uint32_t)tid)) << 47;
  }
  __syncthreads();
  const uint64_t thr = s_thr;  // 0 => select all (fewer than TOPK candidates)
  uint32_t i = blockIdx.x * 1024 + tid;
  if (i < n) {
    uint64_t key = cand[(size_t)b * CAND_CAP + i];
    if (key >= thr) {
      uint32_t pos = atomicAdd(&cnt_loc, 1u);
      list[pos] = key;
    }
  }
  __syncthreads();
  uint32_t nblk = cnt_loc;
  if (tid == 0 && nblk > 0) base_g = atomicAdd(&sel_count[b], nblk);
  __syncthreads();
  if (nblk > 0 && (uint32_t)tid < nblk) {
    uint32_t pp = base_g + tid;
    if (pp < (uint32_t)SEL_CAP) {
      sel[(size_t)b * SEL_CAP + pp] = list[tid];
      rankg[(size_t)b * SEL_CAP + pp] = 0u;
    }
  }
}

// ---------------- tiled partial ranking ----------------------------------------------
__global__ void __launch_bounds__(RK_ME) k_rank_part(const uint64_t* __restrict__ sel,
                                                     const uint32_t* __restrict__ sel_count,
                                                     uint32_t* __restrict__ rankg) {
  __shared__ uint64_t keys[RK_CH];  // 8 KiB
  const int b = blockIdx.z;
  uint32_t n = sel_count[b];
  if (n > (uint32_t)SEL_CAP) n = SEL_CAP;
  const uint32_t me0 = blockIdx.x * RK_ME;
  const uint32_t c0 = blockIdx.y * RK_CH;
  if (me0 >= n || c0 >= n) return;
  const uint64_t* sb = sel + (size_t)b * SEL_CAP;
  uint32_t clen = n - c0;
  if (clen > (uint32_t)RK_CH) clen = RK_CH;
  for (uint32_t i = threadIdx.x; i < clen; i += RK_ME) keys[i] = sb[c0 + i];
  __syncthreads();
  const uint32_t me = me0 + threadIdx.x;
  if (me >= n) return;
  const uint64_t kme = sb[me];
  uint32_t rank = 0;
  uint32_t i = 0;
  for (; i + 8 <= clen; i += 8) {
    rank += (keys[i] > kme);
    rank += (keys[i + 1] > kme);
    rank += (keys[i + 2] > kme);
    rank += (keys[i + 3] > kme);
    rank += (keys[i + 4] > kme);
    rank += (keys[i + 5] > kme);
    rank += (keys[i + 6] > kme);
    rank += (keys[i + 7] > kme);
  }
  for (; i < clen; ++i) rank += (keys[i] > kme);
  if (rank) atomicAdd(&rankg[(size_t)b * SEL_CAP + me], rank);
}

// ---------------- refinement (scatter fused in): 8 lanes per sel item ----------------
__global__ void __launch_bounds__(256) k_refine(const float* __restrict__ scores,
                                                const uint64_t* __restrict__ sel,
                                                const uint32_t* __restrict__ sel_count,
                                                const uint32_t* __restrict__ rankg,
                                                float* __restrict__ out) {
  int gid = blockIdx.x * 256 + threadIdx.x;
  int idx = gid >> 3, ln = gid & 7;
  const int b = idx / SEL_CAP;
  const int i = idx % SEL_CAP;
  uint32_t n = sel_count[b];
  if (n > (uint32_t)SEL_CAP) n = SEL_CAP;
  if ((uint32_t)i >= n) return;  // uniform across the 8-lane group
  uint32_t r = rankg[(size_t)b * SEL_CAP + i];
  if (r >= (uint32_t)TOPK) return;  // uniform across the group
  uint64_t key = sel[(size_t)b * SEL_CAP + i];
  uint32_t flat = 0xFFFFFFFFu - (uint32_t)(key & 0xFFFFFFFFull);
  if (flat >= (uint32_t)(H * W)) flat = 0;  // safety guard
  const int ix = (int)(flat % W);
  const int iy = (int)(flat / W);
  const float* img = scores + (size_t)b * H * W;

  const int nt = (ln == 0) ? 4 : 3;
  float v[4];
  float mymax = -INFINITY;
#pragma unroll
  for (int q = 0; q < 4; ++q) {
    if (q < nt) {
      int t = ln + 8 * q;
      int y = iy + t / 5 - 2, x = ix + t % 5 - 2;
      float val = ((unsigned)x < (unsigned)W && (unsigned)y < (unsigned)H)
                      ? img[(size_t)y * W + x] : 0.0f;
      v[q] = val;
      mymax = fmaxf(mymax, val);
    }
  }
#pragma unroll
  for (int m = 1; m < 8; m <<= 1) mymax = fmaxf(mymax, __shfl_xor(mymax, m));
  float e[4];
  float sum = 0.f, sx = 0.f, sy = 0.f;
#pragma unroll
  for (int q = 0; q < 4; ++q) {
    if (q < nt) {
      int t = ln + 8 * q;
      float ev = expf((v[q] - mymax) / 0.1f);
      e[q] = ev;
      sum += ev;
      sx += ev * (float)(t % 5 - 2);
      sy += ev * (float)(t / 5 - 2);
    }
  }
#pragma unroll
  for (int m = 1; m < 8; m <<= 1) {
    sum += __shfl_xor(sum, m);
    sx += __shfl_xor(sx, m);
    sy += __shfl_xor(sy, m);
  }
  float rx = sx / sum, ry = sy / sum;
  float dsp = 0.f;
#pragma unroll
  for (int q = 0; q < 4; ++q) {
    if (q < nt) {
      int t = ln + 8 * q;
      float dx = ((float)(t % 5 - 2) - rx) * 0.5f;
      float dy = ((float)(t / 5 - 2) - ry) * 0.5f;
      dsp += e[q] * (dx * dx + dy * dy);
    }
  }
#pragma unroll
  for (int m = 1; m < 8; m <<= 1) dsp += __shfl_xor(dsp, m);
  if (ln != 0) return;
  dsp /= sum;
  float kx = ((float)ix + rx) / 1023.0f * 2.0f - 1.0f;
  float ky = ((float)iy + ry) / 1023.0f * 2.0f - 1.0f;
  float px = (kx + 1.0f) * 0.5f * 1023.0f;
  float py = (ky + 1.0f) * 0.5f * 1023.0f;
  float x0f = floorf(px), y0f = floorf(py);
  float wx1 = px - x0f, wx0 = 1.0f - wx1;
  float wy1 = py - y0f, wy0 = 1.0f - wy1;
  int x0 = (int)x0f, y0 = (int)y0f;
  float sc = 0.0f;
  {
    int xs[2] = {x0, x0 + 1};
    int ys[2] = {y0, y0 + 1};
    float wxs[2] = {wx0, wx1};
    float wys[2] = {wy0, wy1};
#pragma unroll
    for (int yy = 0; yy < 2; ++yy)
#pragma unroll
      for (int xx = 0; xx < 2; ++xx) {
        int xi = xs[xx], yi = ys[yy];
        bool valid = (xi >= 0 && xi < W && yi >= 0 && yi < H);
        int xc = min(max(xi, 0), W - 1);
        int yc = min(max(yi, 0), H - 1);
        float vv = valid ? img[(size_t)yc * W + xc] : 0.0f;
        sc += vv * (wxs[xx] * wys[yy]);
      }
  }
  out[((size_t)b * TOPK + r) * 2 + 0] = kx;
  out[((size_t)b * TOPK + r) * 2 + 1] = ky;
  out[(size_t)B * TOPK * 2 + (size_t)b * TOPK + r] = sc;
  out[(size_t)B * TOPK * 3 + (size_t)b * TOPK + r] = dsp;
}

}  // namespace

extern "C" void kernel_launch(void* const* d_in, const int* in_sizes, int n_in,
                              void* d_out, int out_size, void* d_ws, size_t ws_size,
                              hipStream_t stream) {
  const float* scores = (const float*)d_in[0];
  float* out = (float*)d_out;
  char* ws = (char*)d_ws;

  uint32_t* cnt = (uint32_t*)(ws + OFF_CNT);
  uint32_t* cand_count = cnt;                    // [B]
  uint32_t* sel_count  = cnt + 8;                // [B]
  uint32_t* gehist = (uint32_t*)(ws + OFF_EH);   // [B][256]
  uint32_t* gfhist = (uint32_t*)(ws + OFF_FH);   // [B][256]
  uint32_t* rankg = (uint32_t*)(ws + OFF_RANK);  // [B][SEL_CAP]
  uint64_t* sel  = (uint64_t*)(ws + OFF_SEL);
  uint64_t* cand = (uint64_t*)(ws + OFF_CAND);

  hipMemsetAsync(ws + OFF_CNT, 0, MEMSET_BYTES, stream);

  k_nms<<<dim3(W / 64, H / 64, B), 256, 0, stream>>>(scores, cand, cand_count, gehist);
  k_fhist<<<dim3(NHB, B), 256, 0, stream>>>(cand, cand_count, gehist, gfhist);
  k_compact<<<dim3(CAND_CAP / 1024, B), 1024, 0, stream>>>(cand, cand_count, gehist,
                                                           gfhist, sel, sel_count, rankg);
  k_rank_part<<<dim3(SEL_CAP / RK_ME, SEL_CAP / RK_CH, B), RK_ME, 0, stream>>>(
      sel, sel_count, rankg);
  k_refine<<<(B * SEL_CAP * 8) / 256, 256, 0, stream>>>(scores, sel, sel_count, rankg,
                                                        out);
}

// Round 14
// 187.988 us; speedup vs baseline: 6.1170x; 1.0399x over previous
//
#include <hip/hip_runtime.h>
#include <stdint.h>

namespace {

constexpr int B = 8;
constexpr int H = 1024;
constexpr int W = 1024;
constexpr int TOPK = 4096;
constexpr int CAND_CAP = 131072;  // per batch
constexpr int SEL_CAP = 16384;    // per batch
constexpr int LIST_CAP = 320;     // per 64x64 tile

// Single-level fine histogram (round-14): bucket = (score_bits>>15) - (112<<8),
// clamped to 0. Covers exp 112..126 x mantissa-8 = 3840 bins (scores >= ~3e-5;
// candidates are maxima of >=25 uniforms so P(score < 3e-5) ~ 0; bin 0 aggregates
// any underflow -> threshold there = select-all, correctness preserved). Built in
// k_nms's tail reusing S (dead after pass 2, 6240 words >= 3840) -> k_fhist GONE.
// Same 1/512 near-1.0 resolution as the proven two-level scheme.
constexpr int HIST_BINS = 3840;
constexpr int HIST_BASE = 112 << 8;  // 28672

// fused-NMS tile: 64x64 interior, radius-8 staged halo (round-12 validity chain:
// M0/M1 computed rows [4,75]; emission rows [8,71] = gy in [y0,y0+63]).
constexpr int RROWS = 78;   // staged score rows (gy = y0-8+r)
constexpr int NG = 20;      // float4 col-groups (80 cols, gx0 = x0-8+4G)
constexpr int STR = 80;     // score row stride (floats)
constexpr int MW = 5;       // mask words/row (3 used + 2 zero pad; stride-5 debanks)
constexpr int NSM = 9;      // mask-pass strips: r0 = 4+8s -> rows 4..75
constexpr int NSE = 8;      // emission strips:  r0 = 8+8s -> rows 8..71
constexpr int NUNIT_M = NG * NSM;  // 180
constexpr int NUNIT_E = NG * NSE;  // 160
// Round-13 lesson: __launch_bounds__(256,5) caused scratch spills of the ring
// state (VALUBusy 59->27%, 64->106us). Keep min-4.

// rank kernel tiling (round-5 lesson: 2D (me,chunk) split keeps ~680 blocks active)
constexpr int RK_ME = 256;   // me-keys per block (1/thread)
constexpr int RK_CH = 1024;  // chunk keys staged in LDS per block

// workspace layout (bytes).
// Round-9 lesson: cooperative grid.sync on 8-XCD MI355X costs ~200us/sync —
// kernel boundaries are CHEAPER than grid syncs; stay multi-kernel (now 4 kernels).
constexpr size_t OFF_CNT   = 0;                                    // 4 KiB
constexpr size_t OFF_GH    = 4096;                                 // B*3840*4 = 120 KiB
constexpr size_t OFF_RANK  = OFF_GH + (size_t)B * HIST_BINS * 4;   // 512 KiB
constexpr size_t OFF_SEL   = OFF_RANK + (size_t)B * SEL_CAP * 4;   // 1 MiB
constexpr size_t OFF_CAND  = OFF_SEL + (size_t)B * SEL_CAP * 8;    // 8 MiB
constexpr size_t MEMSET_BYTES = OFF_RANK;  // cnt page + ghist (124 KiB)

__device__ __forceinline__ float max5(float a, float b, float c, float d, float e) {
  return fmaxf(fmaxf(fmaxf(a, b), fmaxf(c, d)), e);
}
__device__ __forceinline__ float4 ld4(const float* p) {
  return *reinterpret_cast<const float4*>(p);
}

// One unit: col-group G in [0,NG), strip s -> output rows r0..r0+7, where
// r0 = 4+8s for mask passes (0/1) and 8+8s for emission (2). PASS 0: plain
// local-max -> M0. PASS 1/2: inline dilation of the previous mask via a
// 2-row-lookahead ring. PASS 1 writes cumulative M1 = M0|new. PASS 2 emits
// candidates into the LDS list (overflow keys append+hist globally — rare).
template <int PASS>
__device__ __forceinline__ void score_pass(
    int u, int x0, int y0, const float* __restrict__ S,
    const uint32_t* __restrict__ MIN_, uint32_t* __restrict__ MOUT,
    uint64_t* list, uint32_t* cnt_loc, uint64_t* cand, uint32_t* cand_count,
    uint32_t* __restrict__ ghist, int b) {
  const int G = u % NG, s = u / NG;
  const int r0 = ((PASS == 2) ? 8 : 4) + 8 * s;
  const int gx0 = x0 - 8 + 4 * G;
  uint32_t colm = 0;
#pragma unroll
  for (int j = 0; j < 4; ++j)
    if ((unsigned)(gx0 + j) < (unsigned)W) colm |= 1u << j;

  // 16-col mask window starting at p2 = 4G-6 (covers 5-wide OR for 12 score cols)
  const int p2 = 4 * G - 6;
  const int pw2 = (p2 < 0) ? 0 : (p2 >> 5);
  const int psh2 = (p2 < 0) ? 0 : (p2 & 31);
  const int pls2 = (p2 < 0) ? -p2 : 0;

  float4 hw[5], cw[5];
  uint32_t snr[5], mor[5], cnb[5];
  constexpr int NK = (PASS == 0) ? 12 : 16;
#pragma unroll
  for (int k = 0; k < NK; ++k) {
    if (PASS != 0) {
      const int mr = r0 - 4 + k;
      uint32_t morrow = 0, cnib = 0;
      if ((unsigned)mr < (unsigned)RROWS) {
        const uint32_t* srow = MIN_ + mr * MW;
        uint64_t X = (uint64_t)srow[pw2] | ((uint64_t)srow[pw2 + 1] << 32);
        uint64_t win = pls2 ? (X << pls2) : (X >> psh2);
        uint64_t t5 = win | (win >> 1) | (win >> 2) | (win >> 3) | (win >> 4);
        morrow = (uint32_t)t5 & 0xFFFu;
        cnib = (uint32_t)(win >> 6) & 0xFu;
      }
      mor[k % 5] = morrow;
      cnb[k % 5] = cnib;
    }
    const int ks = (PASS == 0) ? k : k - 4;
    if (ks >= 0) {
      const int sr = r0 - 2 + ks;
      uint32_t supp = 0;
      if (PASS != 0) supp = mor[0] | mor[1] | mor[2] | mor[3] | mor[4];
      const float* rowp = S + sr * STR + 4 * G;
      float4 d = ld4(rowp);
      float4 a = (G > 0) ? ld4(rowp - 4) : d;  // garbage-only cols, safe
      float4 e = (G < NG - 1) ? ld4(rowp + 4) : d;
      if (PASS != 0) {
        if (supp & 0x001u) a.x = 0.f;
        if (supp & 0x002u) a.y = 0.f;
        if (supp & 0x004u) a.z = 0.f;
        if (supp & 0x008u) a.w = 0.f;
        if (supp & 0x010u) d.x = 0.f;
        if (supp & 0x020u) d.y = 0.f;
        if (supp & 0x040u) d.z = 0.f;
        if (supp & 0x080u) d.w = 0.f;
        if (supp & 0x100u) e.x = 0.f;
        if (supp & 0x200u) e.y = 0.f;
        if (supp & 0x400u) e.z = 0.f;
        if (supp & 0x800u) e.w = 0.f;
      }
      float4 hm;
      hm.x = max5(a.z, a.w, d.x, d.y, d.z);
      hm.y = max5(a.w, d.x, d.y, d.z, d.w);
      hm.z = max5(d.x, d.y, d.z, d.w, e.x);
      hm.w = max5(d.y, d.z, d.w, e.x, e.y);
      hw[ks % 5] = hm;
      cw[ks % 5] = d;
      snr[ks % 5] = (supp >> 4) & 0xFu;
      if (ks >= 4) {
        const int rq = r0 - 4 + ks;  // output row: r0..r0+7
        const int gy = y0 - 8 + rq;
        float4 vm;
        vm.x = max5(hw[0].x, hw[1].x, hw[2].x, hw[3].x, hw[4].x);
        vm.y = max5(hw[0].y, hw[1].y, hw[2].y, hw[3].y, hw[4].y);
        vm.z = max5(hw[0].z, hw[1].z, hw[2].z, hw[3].z, hw[4].z);
        vm.w = max5(hw[0].w, hw[1].w, hw[2].w, hw[3].w, hw[4].w);
        float4 c = cw[(ks + 3) % 5];  // center (masked for PASS 1/2)
        uint32_t nm = (uint32_t)(c.x == vm.x) | ((uint32_t)(c.y == vm.y) << 1) |
                      ((uint32_t)(c.z == vm.z) << 2) | ((uint32_t)(c.w == vm.w) << 3);
        nm &= ((unsigned)gy < (unsigned)H) ? colm : 0u;
        const int widx = rq * MW + (G >> 3);
        const int shift = 4 * (G & 7);
        if (PASS == 0) {
          if (nm) atomicOr(&MOUT[widx], nm << shift);
        } else if (PASS == 1) {
          uint32_t fin = cnb[ks % 5] | (nm & ~snr[(ks + 3) % 5]);
          if (fin) atomicOr(&MOUT[widx], fin << shift);
        } else {
          uint32_t fin = cnb[ks % 5] | (nm & ~snr[(ks + 3) % 5]);
          if (fin && G >= 2 && G < 18 && gy >= 2 && gy < H - 2) {
#pragma unroll
            for (int j = 0; j < 4; ++j) {
              if ((fin >> j) & 1u) {
                int gx = gx0 + j;
                if (gx >= 2 && gx < W - 2) {
                  float sval = S[rq * STR + 4 * G + j];  // original (unmasked) score
                  if (sval > 0.0f) {
                    uint32_t bits = __float_as_uint(sval);
                    uint32_t flat = (uint32_t)(gy * W + gx);
                    uint64_t key = ((uint64_t)bits << 32) | (uint64_t)(0xFFFFFFFFu - flat);
                    uint32_t pos = atomicAdd(cnt_loc, 1u);
                    if (pos < (uint32_t)LIST_CAP) {
                      list[pos] = key;
                    } else {  // tie overflow: direct global append + hist (rare)
                      uint32_t pp = atomicAdd(&cand_count[b], 1u);
                      if (pp < (uint32_t)CAND_CAP) cand[(size_t)b * CAND_CAP + pp] = key;
                      int bin = (int)(bits >> 15) - HIST_BASE;
                      if (bin < 0) bin = 0;
                      if (bin >= HIST_BINS) bin = HIST_BINS - 1;
                      atomicAdd(&ghist[(size_t)b * HIST_BINS + bin], 1u);
                    }
                  }
                }
              }
            }
          }
        }
      }
    }
  }
}

// ---------------- fused 3-pass NMS + candidate emit + fine-hist tail -----------------
__global__ void __launch_bounds__(256, 4) k_nms(const float* __restrict__ scores,
                                                uint64_t* __restrict__ cand,
                                                uint32_t* __restrict__ cand_count,
                                                uint32_t* __restrict__ ghist) {
  __shared__ float S[RROWS * STR];
  __shared__ uint32_t M0s[RROWS * MW];
  __shared__ uint32_t M1s[RROWS * MW];
  __shared__ uint64_t list[LIST_CAP];
  __shared__ uint32_t cnt_loc, base_g;
  const int b = blockIdx.z;
  const int x0 = blockIdx.x * 64, y0 = blockIdx.y * 64;
  const int tid = threadIdx.x;
  const float* img = scores + (size_t)b * H * W;
  if (tid == 0) cnt_loc = 0;

  for (int u = tid; u < RROWS * NG; u += 256) {
    int r = u / NG, G = u % NG;
    int gy = y0 - 8 + r, gx = x0 - 8 + 4 * G;
    float4 v;
    if ((unsigned)gy < (unsigned)H && (unsigned)gx < (unsigned)W)
      v = ld4(img + (size_t)gy * W + gx);
    else
      v = make_float4(-INFINITY, -INFINITY, -INFINITY, -INFINITY);
    *reinterpret_cast<float4*>(&S[r * STR + 4 * G]) = v;
  }
  for (int i = tid; i < RROWS * MW; i += 256) {
    M0s[i] = 0;
    M1s[i] = 0;
  }
  __syncthreads();
  if (tid < NUNIT_M)
    score_pass<0>(tid, x0, y0, S, nullptr, M0s, nullptr, nullptr, nullptr, nullptr,
                  nullptr, b);
  __syncthreads();
  if (tid < NUNIT_M)
    score_pass<1>(tid, x0, y0, S, M0s, M1s, nullptr, nullptr, nullptr, nullptr,
                  nullptr, b);
  __syncthreads();
  if (tid < NUNIT_E)
    score_pass<2>(tid, x0, y0, S, M1s, nullptr, list, &cnt_loc, cand, cand_count,
                  ghist, b);
  __syncthreads();
  // tail: copy list -> cand, build 3840-bin fine hist in S (dead after pass 2)
  uint32_t nblk = cnt_loc;
  uint32_t nmain = nblk < (uint32_t)LIST_CAP ? nblk : (uint32_t)LIST_CAP;
  if (tid == 0) base_g = atomicAdd(&cand_count[b], nmain);
  uint32_t* Shist = (uint32_t*)S;
  for (int i = tid; i < HIST_BINS; i += 256) Shist[i] = 0;
  __syncthreads();
  uint32_t bg = base_g;
  for (uint32_t i = tid; i < nmain; i += 256) {
    uint64_t key = list[i];
    uint32_t pp = bg + i;
    if (pp < (uint32_t)CAND_CAP) cand[(size_t)b * CAND_CAP + pp] = key;
    int bin = (int)(uint32_t)(key >> 47) - HIST_BASE;  // = (score_bits>>15)-28672
    if (bin < 0) bin = 0;
    atomicAdd(&Shist[bin], 1u);
  }
  __syncthreads();
  for (int i = tid; i < HIST_BINS; i += 256) {
    uint32_t v = Shist[i];
    if (v) atomicAdd(&ghist[(size_t)b * HIST_BINS + i], v);  // ~20 sparse bins/block
  }
}

// ---------------- compact (threshold-find fused in, single-level hist) ---------------
// Each live block recomputes thr from ghist with a 960-wide suffix scan (redundant
// across blocks but fully parallel), filters its 1024-candidate slice, and zeroes
// rankg for every sel slot written. Dead blocks (beyond cand count) exit early.
__global__ void __launch_bounds__(1024) k_compact(const uint64_t* __restrict__ cand,
                                                  const uint32_t* __restrict__ cand_count,
                                                  const uint32_t* __restrict__ ghist,
                                                  uint64_t* __restrict__ sel,
                                                  uint32_t* __restrict__ sel_count,
                                                  uint32_t* __restrict__ rankg) {
  __shared__ uint64_t list[1024];
  __shared__ uint32_t cnt_loc, base_g;
  __shared__ uint32_t h[1024];
  __shared__ uint64_t s_thr;
  const int b = blockIdx.y;
  uint32_t n = cand_count[b];
  if (n > (uint32_t)CAND_CAP) n = CAND_CAP;
  if (blockIdx.x * 1024u >= n) return;  // dead block: skip redundant scan
  const int tid = threadIdx.x;
  if (tid == 0) {
    cnt_loc = 0;
    s_thr = 0ull;
  }
  // bins 4*tid .. 4*tid+3 (3840/4 = 960 loaders)
  const uint32_t* gh = ghist + (size_t)b * HIST_BINS;
  uint4 mybins = make_uint4(0u, 0u, 0u, 0u);
  uint32_t s = 0;
  if (tid < HIST_BINS / 4) {
    mybins = reinterpret_cast<const uint4*>(gh)[tid];
    s = mybins.x + mybins.y + mybins.z + mybins.w;
  }
  h[tid] = s;
  __syncthreads();
  for (int d = 1; d < 1024; d <<= 1) {
    uint32_t v = (tid + d < 1024) ? h[tid + d] : 0u;
    __syncthreads();
    h[tid] += v;
    __syncthreads();
  }
  {
    uint32_t cum = h[tid];                         // count in bins >= 4*tid
    uint32_t nxt = (tid < 1023) ? h[tid + 1] : 0u; // count in bins >= 4*(tid+1)
    if (cum >= (uint32_t)TOPK && nxt < (uint32_t)TOPK) {
      uint32_t run = nxt;
      uint32_t binv[4] = {mybins.x, mybins.y, mybins.z, mybins.w};
      int thrbin = 4 * tid;
#pragma unroll
      for (int j = 3; j >= 0; --j) {
        run += binv[j];
        if (run >= (uint32_t)TOPK) {
          thrbin = 4 * tid + j;
          break;
        }
      }
      if (thrbin > 0)
        s_thr = ((uint64_t)(uint32_t)(thrbin + HIST_BASE)) << 47;
      // thrbin == 0: underflow aggregate -> thr 0 (select all)
    }
  }
  __syncthreads();
  const uint64_t thr = s_thr;  // 0 => select all (fewer than TOPK, or bin-0 thr)
  uint32_t i = blockIdx.x * 1024 + tid;
  if (i < n) {
    uint64_t key = cand[(size_t)b * CAND_CAP + i];
    if (key >= thr) {
      uint32_t pos = atomicAdd(&cnt_loc, 1u);
      list[pos] = key;
    }
  }
  __syncthreads();
  uint32_t nblk = cnt_loc;
  if (tid == 0 && nblk > 0) base_g = atomicAdd(&sel_count[b], nblk);
  __syncthreads();
  if (nblk > 0 && (uint32_t)tid < nblk) {
    uint32_t pp = base_g + tid;
    if (pp < (uint32_t)SEL_CAP) {
      sel[(size_t)b * SEL_CAP + pp] = list[tid];
      rankg[(size_t)b * SEL_CAP + pp] = 0u;
    }
  }
}

// ---------------- tiled partial ranking ----------------------------------------------
__global__ void __launch_bounds__(RK_ME) k_rank_part(const uint64_t* __restrict__ sel,
                                                     const uint32_t* __restrict__ sel_count,
                                                     uint32_t* __restrict__ rankg) {
  __shared__ uint64_t keys[RK_CH];  // 8 KiB
  const int b = blockIdx.z;
  uint32_t n = sel_count[b];
  if (n > (uint32_t)SEL_CAP) n = SEL_CAP;
  const uint32_t me0 = blockIdx.x * RK_ME;
  const uint32_t c0 = blockIdx.y * RK_CH;
  if (me0 >= n || c0 >= n) return;
  const uint64_t* sb = sel + (size_t)b * SEL_CAP;
  uint32_t clen = n - c0;
  if (clen > (uint32_t)RK_CH) clen = RK_CH;
  for (uint32_t i = threadIdx.x; i < clen; i += RK_ME) keys[i] = sb[c0 + i];
  __syncthreads();
  const uint32_t me = me0 + threadIdx.x;
  if (me >= n) return;
  const uint64_t kme = sb[me];
  uint32_t rank = 0;
  uint32_t i = 0;
  for (; i + 8 <= clen; i += 8) {
    rank += (keys[i] > kme);
    rank += (keys[i + 1] > kme);
    rank += (keys[i + 2] > kme);
    rank += (keys[i + 3] > kme);
    rank += (keys[i + 4] > kme);
    rank += (keys[i + 5] > kme);
    rank += (keys[i + 6] > kme);
    rank += (keys[i + 7] > kme);
  }
  for (; i < clen; ++i) rank += (keys[i] > kme);
  if (rank) atomicAdd(&rankg[(size_t)b * SEL_CAP + me], rank);
}

// ---------------- refinement (scatter fused in): 8 lanes per sel item ----------------
__global__ void __launch_bounds__(256) k_refine(const float* __restrict__ scores,
                                                const uint64_t* __restrict__ sel,
                                                const uint32_t* __restrict__ sel_count,
                                                const uint32_t* __restrict__ rankg,
                                                float* __restrict__ out) {
  int gid = blockIdx.x * 256 + threadIdx.x;
  int idx = gid >> 3, ln = gid & 7;
  const int b = idx / SEL_CAP;
  const int i = idx % SEL_CAP;
  uint32_t n = sel_count[b];
  if (n > (uint32_t)SEL_CAP) n = SEL_CAP;
  if ((uint32_t)i >= n) return;  // uniform across the 8-lane group
  uint32_t r = rankg[(size_t)b * SEL_CAP + i];
  if (r >= (uint32_t)TOPK) return;  // uniform across the group
  uint64_t key = sel[(size_t)b * SEL_CAP + i];
  uint32_t flat = 0xFFFFFFFFu - (uint32_t)(key & 0xFFFFFFFFull);
  if (flat >= (uint32_t)(H * W)) flat = 0;  // safety guard
  const int ix = (int)(flat % W);
  const int iy = (int)(flat / W);
  const float* img = scores + (size_t)b * H * W;

  const int nt = (ln == 0) ? 4 : 3;
  float v[4];
  float mymax = -INFINITY;
#pragma unroll
  for (int q = 0; q < 4; ++q) {
    if (q < nt) {
      int t = ln + 8 * q;
      int y = iy + t / 5 - 2, x = ix + t % 5 - 2;
      float val = ((unsigned)x < (unsigned)W && (unsigned)y < (unsigned)H)
                      ? img[(size_t)y * W + x] : 0.0f;
      v[q] = val;
      mymax = fmaxf(mymax, val);
    }
  }
#pragma unroll
  for (int m = 1; m < 8; m <<= 1) mymax = fmaxf(mymax, __shfl_xor(mymax, m));
  float e[4];
  float sum = 0.f, sx = 0.f, sy = 0.f;
#pragma unroll
  for (int q = 0; q < 4; ++q) {
    if (q < nt) {
      int t = ln + 8 * q;
      float ev = expf((v[q] - mymax) / 0.1f);
      e[q] = ev;
      sum += ev;
      sx += ev * (float)(t % 5 - 2);
      sy += ev * (float)(t / 5 - 2);
    }
  }
#pragma unroll
  for (int m = 1; m < 8; m <<= 1) {
    sum += __shfl_xor(sum, m);
    sx += __shfl_xor(sx, m);
    sy += __shfl_xor(sy, m);
  }
  float rx = sx / sum, ry = sy / sum;
  float dsp = 0.f;
#pragma unroll
  for (int q = 0; q < 4; ++q) {
    if (q < nt) {
      int t = ln + 8 * q;
      float dx = ((float)(t % 5 - 2) - rx) * 0.5f;
      float dy = ((float)(t / 5 - 2) - ry) * 0.5f;
      dsp += e[q] * (dx * dx + dy * dy);
    }
  }
#pragma unroll
  for (int m = 1; m < 8; m <<= 1) dsp += __shfl_xor(dsp, m);
  if (ln != 0) return;
  dsp /= sum;
  float kx = ((float)ix + rx) / 1023.0f * 2.0f - 1.0f;
  float ky = ((float)iy + ry) / 1023.0f * 2.0f - 1.0f;
  float px = (kx + 1.0f) * 0.5f * 1023.0f;
  float py = (ky + 1.0f) * 0.5f * 1023.0f;
  float x0f = floorf(px), y0f = floorf(py);
  float wx1 = px - x0f, wx0 = 1.0f - wx1;
  float wy1 = py - y0f, wy0 = 1.0f - wy1;
  int x0 = (int)x0f, y0 = (int)y0f;
  float sc = 0.0f;
  {
    int xs[2] = {x0, x0 + 1};
    int ys[2] = {y0, y0 + 1};
    float wxs[2] = {wx0, wx1};
    float wys[2] = {wy0, wy1};
#pragma unroll
    for (int yy = 0; yy < 2; ++yy)
#pragma unroll
      for (int xx = 0; xx < 2; ++xx) {
        int xi = xs[xx], yi = ys[yy];
        bool valid = (xi >= 0 && xi < W && yi >= 0 && yi < H);
        int xc = min(max(xi, 0), W - 1);
        int yc = min(max(yi, 0), H - 1);
        float vv = valid ? img[(size_t)yc * W + xc] : 0.0f;
        sc += vv * (wxs[xx] * wys[yy]);
      }
  }
  out[((size_t)b * TOPK + r) * 2 + 0] = kx;
  out[((size_t)b * TOPK + r) * 2 + 1] = ky;
  out[(size_t)B * TOPK * 2 + (size_t)b * TOPK + r] = sc;
  out[(size_t)B * TOPK * 3 + (size_t)b * TOPK + r] = dsp;
}

}  // namespace

extern "C" void kernel_launch(void* const* d_in, const int* in_sizes, int n_in,
                              void* d_out, int out_size, void* d_ws, size_t ws_size,
                              hipStream_t stream) {
  const float* scores = (const float*)d_in[0];
  float* out = (float*)d_out;
  char* ws = (char*)d_ws;

  uint32_t* cnt = (uint32_t*)(ws + OFF_CNT);
  uint32_t* cand_count = cnt;                    // [B]
  uint32_t* sel_count  = cnt + 8;                // [B]
  uint32_t* ghist = (uint32_t*)(ws + OFF_GH);    // [B][HIST_BINS]
  uint32_t* rankg = (uint32_t*)(ws + OFF_RANK);  // [B][SEL_CAP]
  uint64_t* sel  = (uint64_t*)(ws + OFF_SEL);
  uint64_t* cand = (uint64_t*)(ws + OFF_CAND);

  hipMemsetAsync(ws + OFF_CNT, 0, MEMSET_BYTES, stream);

  k_nms<<<dim3(W / 64, H / 64, B), 256, 0, stream>>>(scores, cand, cand_count, ghist);
  k_compact<<<dim3(CAND_CAP / 1024, B), 1024, 0, stream>>>(cand, cand_count, ghist,
                                                           sel, sel_count, rankg);
  k_rank_part<<<dim3(SEL_CAP / RK_ME, SEL_CAP / RK_CH, B), RK_ME, 0, stream>>>(
      sel, sel_count, rankg);
  k_refine<<<(B * SEL_CAP * 8) / 256, 256, 0, stream>>>(scores, sel, sel_count, rankg,
                                                        out);
}